// Round 11
// baseline (489.976 us; speedup 1.0000x reference)
//
#include <hip/hip_runtime.h>

#define NN 4096
#define NNP 4128   // padded row stride (shorts) to break 8KB channel aliasing
#define BROW 132   // bits row stride in u32 (528B, breaks 512B aliasing)
#define HEADS 4
#define H1PER 30
#define H1DIM 120
#define H2DIM 50

typedef short short8_t __attribute__((ext_vector_type(8)));
typedef float f32x4 __attribute__((ext_vector_type(4)));

__device__ __forceinline__ float lrelu(float x) { return x > 0.f ? x : 0.1f * x; }

__device__ __forceinline__ unsigned short bfrne(float x) {
  unsigned u = __float_as_uint(x);
  u += 0x7fffu + ((u >> 16) & 1u);
  return (unsigned short)(u >> 16);
}
__device__ __forceinline__ unsigned bfpk_rne(float lo, float hi) {
  return (unsigned)bfrne(lo) | ((unsigned)bfrne(hi) << 16);
}
__device__ __forceinline__ unsigned bfpk(float lo, float hi) {
  unsigned a = (__float_as_uint(lo) + 0x8000u) >> 16;
  unsigned b = (__float_as_uint(hi) + 0x8000u) & 0xffff0000u;
  return a | b;
}
// monotone float<->uint encoding for atomicMax-based float max
__device__ __forceinline__ unsigned fenc(float x) {
  unsigned u = __float_as_uint(x);
  return (u & 0x80000000u) ? ~u : (u | 0x80000000u);
}
__device__ __forceinline__ float fdec(unsigned u) {
  return (u & 0x80000000u) ? __uint_as_float(u ^ 0x80000000u) : __uint_as_float(~u);
}

#define GL16(g, l)                                                                        \
  __builtin_amdgcn_global_load_lds((const __attribute__((address_space(1))) unsigned int*)(g), \
                                   (__attribute__((address_space(3))) unsigned int*)(l), 16, 0, 0)

// ---------------- prep: W1 -> bf16 w1t[128][NNP] + f1/f2 features + mxu init ----------------
__global__ __launch_bounds__(256) void k_pre(const float* __restrict__ W1,
                                             const float* __restrict__ a1s,
                                             const float* __restrict__ a1d,
                                             unsigned short* __restrict__ w1t,
                                             unsigned* __restrict__ mxu) {
  int t = threadIdx.x;
  if (blockIdx.x == 0 && t < 8) mxu[t] = 0;  // encoded-domain minimum
  int k = blockIdx.x * 256 + t;
#pragma unroll
  for (int h = 0; h < 4; ++h) {
    const float* wp = W1 + ((size_t)h * 4096 + k) * H1PER;
    float fs = 0.f, fd = 0.f;
#pragma unroll
    for (int oo = 0; oo < H1PER; ++oo) {
      float v = wp[oo];
      w1t[(size_t)(h * 30 + oo) * NNP + k] = bfrne(v);
      fs += v * a1s[h * H1PER + oo];
      fd += v * a1d[h * H1PER + oo];
    }
    w1t[(size_t)(120 + h) * NNP + k] = bfrne(fs);
    w1t[(size_t)(124 + h) * NNP + k] = bfrne(fd);
  }
}

// ---------------- MERGED: MFMA GEMM1 (blocks 0..255) + adj->bits (blocks 256..16639) ----------------
// GEMM: BM=128, BK=32, double-buffered, counted vmcnt(6) (R10 body, refcheck-proven).
// Bits blocks are pure-BW and overlap gemm's latency stalls; bits output first read 2 dispatches later.
__global__ __launch_bounds__(256) void k_gb(const float* __restrict__ x,
                                            const unsigned short* __restrict__ w1t,
                                            float* __restrict__ part,
                                            const int* __restrict__ adj,
                                            unsigned long long* __restrict__ bits) {
  const int t = threadIdx.x;
  __shared__ float xs[2][128 * 32];            // A: 16 KB/buf
  __shared__ unsigned short bs[2][128 * 32];   // B: 8 KB/buf
  if (blockIdx.x >= 256) {
    // ---- bits path (no LDS use) ----
    int id = blockIdx.x - 256;
    int n = id >> 2, r = id & 3;
    size_t base = (size_t)n * 4096 + r * 1024;
    int v0 = adj[base + t];
    int v1 = adj[base + 256 + t];
    int v2 = adj[base + 512 + t];
    int v3 = adj[base + 768 + t];
    unsigned long long m0 = __ballot(v0 > 0);
    unsigned long long m1 = __ballot(v1 > 0);
    unsigned long long m2 = __ballot(v2 > 0);
    unsigned long long m3 = __ballot(v3 > 0);
    if ((t & 63) == 0) {
      size_t w = (size_t)n * (BROW / 2) + r * 16 + (t >> 6);
      bits[w] = m0;
      bits[w + 4] = m1;
      bits[w + 8] = m2;
      bits[w + 12] = m3;
    }
    return;
  }
  // ---- gemm path ----
  const int lane = t & 63, wave = t >> 6;
  const int m = lane & 15, q = lane >> 4;
  const int i0 = (blockIdx.x & 31) * 128;
  const int kz = (blockIdx.x >> 5) * 512;
  const int ar_ = t >> 3, ac_ = t & 7;
  const float* gxa = x + (size_t)(i0 + ar_) * 4096 + kz + ((ac_ ^ (ar_ & 7)) * 4);
  const int br_ = t >> 2;
  const int bsw = (br_ & 3) ^ ((br_ >> 2) & 3);
  const unsigned short* gwb = w1t + (size_t)br_ * NNP + kz + ((t & 3) ^ bsw) * 8;
  const int asw = m & 7;
  f32x4 acc[2][8];
#pragma unroll
  for (int rg = 0; rg < 2; ++rg)
#pragma unroll
    for (int nt = 0; nt < 8; ++nt) acc[rg][nt] = (f32x4){0.f, 0.f, 0.f, 0.f};

  auto STAGE = [&](int buf, int kk) {
#pragma unroll
    for (int i = 0; i < 4; ++i)
      GL16(gxa + (size_t)i * 32 * 4096 + kk, &xs[buf][(i * 32 + ar_) * 32 + ac_ * 4]);
#pragma unroll
    for (int i = 0; i < 2; ++i)
      GL16(gwb + (size_t)i * 64 * NNP + kk, &bs[buf][(i * 64 + br_) * 32 + (t & 3) * 8]);
  };

  STAGE(0, 0);  // prologue
#pragma unroll
  for (int it = 0; it < 16; ++it) {
    const int cur = it & 1;
    if (it < 15) {
      STAGE(cur ^ 1, (it + 1) * 32);
      asm volatile("s_waitcnt vmcnt(6)" ::: "memory");  // current step's 6 done; next 6 in flight
    } else {
      asm volatile("s_waitcnt vmcnt(0)" ::: "memory");
    }
    __builtin_amdgcn_s_barrier();
    __builtin_amdgcn_sched_barrier(0);
    const int c0 = q * 2;
    union { short8_t v; unsigned u[4]; } A[2];
#pragma unroll
    for (int rg = 0; rg < 2; ++rg) {
      const int arow = wave * 32 + rg * 16 + m;  // arow&7 == m&7
      float4 a0 = *(const float4*)&xs[cur][arow * 32 + ((c0 ^ asw) * 4)];
      float4 a1 = *(const float4*)&xs[cur][arow * 32 + (((c0 + 1) ^ asw) * 4)];
      A[rg].u[0] = bfpk_rne(a0.x, a0.y);
      A[rg].u[1] = bfpk_rne(a0.z, a0.w);
      A[rg].u[2] = bfpk_rne(a1.x, a1.y);
      A[rg].u[3] = bfpk_rne(a1.z, a1.w);
    }
#pragma unroll
    for (int nt = 0; nt < 8; ++nt) {
      const int f = nt * 16 + m;
      const int fsw = (f & 3) ^ ((f >> 2) & 3);
      short8_t B = *(const short8_t*)&bs[cur][f * 32 + ((q ^ fsw) * 8)];
      acc[0][nt] = __builtin_amdgcn_mfma_f32_16x16x32_bf16(A[0].v, B, acc[0][nt], 0, 0, 0);
      acc[1][nt] = __builtin_amdgcn_mfma_f32_16x16x32_bf16(A[1].v, B, acc[1][nt], 0, 0, 0);
    }
    __builtin_amdgcn_sched_barrier(0);
    __builtin_amdgcn_s_barrier();
  }
  float* pp = part + ((size_t)(blockIdx.x >> 5) * 4096 + i0 + wave * 32 + q * 4) * 128 + m;
#pragma unroll
  for (int rg = 0; rg < 2; ++rg)
#pragma unroll
    for (int nt = 0; nt < 8; ++nt)
#pragma unroll
      for (int r = 0; r < 4; ++r) pp[(rg * 16 + r) * 128 + nt * 16] = acc[rg][nt][r];
}

// ---------------- combine 8 k-split partials -> whbt(bf16,T) + f1/f2 + max1(atomic) ----------------
__global__ __launch_bounds__(256) void k_f1c(const float* __restrict__ part,
                                             unsigned short* __restrict__ whbt,
                                             float* __restrict__ f1, float* __restrict__ f2,
                                             unsigned* __restrict__ mxu1) {
  const int t = threadIdx.x;
  const int n = blockIdx.x * 16 + (t >> 4);
  const int og = (t & 15) * 8;
  __shared__ float f2loc[16][4];
  float s[8] = {0.f, 0.f, 0.f, 0.f, 0.f, 0.f, 0.f, 0.f};
  for (int z = 0; z < 8; ++z) {
    const float* pp = part + ((size_t)z * NN + n) * 128 + og;
    float4 u0 = *(const float4*)pp;
    float4 u1 = *(const float4*)(pp + 4);
    s[0] += u0.x; s[1] += u0.y; s[2] += u0.z; s[3] += u0.w;
    s[4] += u1.x; s[5] += u1.y; s[6] += u1.z; s[7] += u1.w;
  }
  if (og < 120) {
#pragma unroll
    for (int j = 0; j < 8; ++j) {
      int o = og + j;
      int h = o / 30, oo = o - h * 30;
      whbt[(size_t)(h * 32 + oo) * NNP + n] = bfrne(s[j]);
    }
  } else {
#pragma unroll
    for (int j = 0; j < 4; ++j) {
      f1[(size_t)j * NN + n] = s[j];
      f2[(size_t)j * NN + n] = s[4 + j];
      f2loc[t >> 4][j] = s[4 + j];
    }
  }
  if ((t & 15) < 8) {
    int h = (t & 15) >> 1, odd = (t & 15) & 1;
    whbt[(size_t)(h * 32 + 30 + odd) * NNP + n] = odd ? 0 : 0x3f80;
  }
  __syncthreads();
  if (t < 4) {
    float m = f2loc[0][t];
#pragma unroll
    for (int i = 1; i < 16; ++i) m = fmaxf(m, f2loc[i][t]);
    atomicMax(&mxu1[t], fenc(m));
  }
}

// ---------------- MFMA attention layer 1: BI=128, LDS-staged B (shared across waves) ----------------
// grid (32 i-blocks, 4 heads, 4 j-split), block 256; each wave covers 32 i-rows (2 row-groups)
__global__ __launch_bounds__(256) void k_att1m(const unsigned short* __restrict__ whbt,
                                               const float* __restrict__ f1, const float* __restrict__ f2,
                                               const unsigned* __restrict__ mxu1,
                                               const unsigned int* __restrict__ bits32,
                                               float* __restrict__ part) {
  const int h = blockIdx.y, js = blockIdx.z;
  const int t = threadIdx.x;
  const int lane = t & 63, wave = t >> 6;
  const int m = lane & 15, q = lane >> 4;
  const int i0w = blockIdx.x * 128 + wave * 32;
  const int jbase = js * 1024;
  const float mxh = fdec(mxu1[h]);
  __shared__ float2 es[1024];
  __shared__ unsigned short bsm1[2][8192];  // 2 x 16KB
  for (int e = t; e < 1024; e += 256) {
    float fv = f2[h * NN + jbase + e] - mxh;
    es[e] = make_float2(__expf(fv), __expf(0.1f * fv));
  }
  float Rr[2];
  const uint4* br[2];
#pragma unroll
  for (int rg = 0; rg < 2; ++rg) {
    const float f1r = f1[h * NN + i0w + rg * 16 + m];
    const float s = f1r + mxh;
    Rr[rg] = __expf(fminf(60.f, -0.9f * s));
    br[rg] = (const uint4*)(bits32 + (size_t)(i0w + rg * 16 + m) * BROW + (jbase >> 5));
  }
  const float2* fp = es;
  const int r_st = t >> 3;
  const unsigned short* gB = whbt + (size_t)(h * 32 + r_st) * NNP + jbase + ((t & 7) ^ (r_st & 7)) * 8;
  f32x4 acc[2][2];
#pragma unroll
  for (int rg = 0; rg < 2; ++rg) {
    acc[rg][0] = (f32x4){0.f, 0.f, 0.f, 0.f};
    acc[rg][1] = (f32x4){0.f, 0.f, 0.f, 0.f};
  }

  __syncthreads();  // es ready

#pragma unroll
  for (int c = 0; c < 4; ++c) GL16(gB + c * 64, &bsm1[0][c * 2048 + t * 8]);

#pragma unroll
  for (int jc = 0; jc < 4; ++jc) {
    const int cur = jc & 1;
    uint4 bqq[2][2];
#pragma unroll
    for (int rg = 0; rg < 2; ++rg) {
      bqq[rg][0] = br[rg][jc * 2];
      bqq[rg][1] = br[rg][jc * 2 + 1];
    }
    if (jc < 3) {
#pragma unroll
      for (int c = 0; c < 4; ++c) GL16(gB + (jc + 1) * 256 + c * 64, &bsm1[cur ^ 1][c * 2048 + t * 8]);
      asm volatile("s_waitcnt vmcnt(4)" ::: "memory");
    } else {
      asm volatile("s_waitcnt vmcnt(0)" ::: "memory");
    }
    __builtin_amdgcn_s_barrier();
    __builtin_amdgcn_sched_barrier(0);
#pragma unroll
    for (int g = 0; g < 2; ++g) {
#pragma unroll
      for (int sub = 0; sub < 4; ++sub) {
        const int jl = (jc * 2 + g) * 128 + sub * 32;
        float4 e01 = *(const float4*)(fp + jl + q * 8);
        float4 e23 = *(const float4*)(fp + jl + q * 8 + 2);
        float4 e45 = *(const float4*)(fp + jl + q * 8 + 4);
        float4 e67 = *(const float4*)(fp + jl + q * 8 + 6);
        const int p = g * 16 + sub * 4 + q;
        short8_t b0 = *(const short8_t*)&bsm1[cur][(p >> 3) * 2048 + m * 64 + ((p & 7) ^ (m & 7)) * 8];
        short8_t b1 = *(const short8_t*)&bsm1[cur][(p >> 3) * 2048 + (m + 16) * 64 + ((p & 7) ^ ((m + 16) & 7)) * 8];
#pragma unroll
        for (int rg = 0; rg < 2; ++rg) {
          const uint4 bq = bqq[rg][g];
          unsigned bsel = (sub == 0 ? bq.x : sub == 1 ? bq.y : sub == 2 ? bq.z : bq.w) >> (q * 8);
          const float R = Rr[rg];
          auto sc = [&](float ep, float en, int jj) {
            float wv = fmaxf(ep, R * en);
            return ((bsel >> jj) & 1u) ? wv : 0.f;
          };
          union { short8_t v; unsigned u[4]; } A;
          A.u[0] = bfpk(sc(e01.x, e01.y, 0), sc(e01.z, e01.w, 1));
          A.u[1] = bfpk(sc(e23.x, e23.y, 2), sc(e23.z, e23.w, 3));
          A.u[2] = bfpk(sc(e45.x, e45.y, 4), sc(e45.z, e45.w, 5));
          A.u[3] = bfpk(sc(e67.x, e67.y, 6), sc(e67.z, e67.w, 7));
          acc[rg][0] = __builtin_amdgcn_mfma_f32_16x16x32_bf16(A.v, b0, acc[rg][0], 0, 0, 0);
          acc[rg][1] = __builtin_amdgcn_mfma_f32_16x16x32_bf16(A.v, b1, acc[rg][1], 0, 0, 0);
        }
      }
    }
    __builtin_amdgcn_sched_barrier(0);
    __builtin_amdgcn_s_barrier();
  }
#pragma unroll
  for (int rg = 0; rg < 2; ++rg) {
    float* pp = part + ((size_t)(js * 4 + h) * NN + i0w + rg * 16 + q * 4) * 32 + m;
#pragma unroll
    for (int r = 0; r < 4; ++r) {
      pp[r * 32] = acc[rg][0][r];
      pp[r * 32 + 16] = acc[rg][1][r];
    }
  }
}

// ---------------- fused: h1 combine + GEMM2 + f2/whbt2 + max2 ----------------
// grid 1024, block 256 (4 waves = 4 nodes)
__global__ __launch_bounds__(256) void k_fuseA(const float* __restrict__ part, const float* __restrict__ b1,
                                               const float* __restrict__ W2, const float* __restrict__ a2s,
                                               const float* __restrict__ a2d,
                                               unsigned short* __restrict__ whbt2,
                                               float* __restrict__ f1b, float* __restrict__ f2b,
                                               unsigned* __restrict__ mxu2) {
  const int t = threadIdx.x;
  __shared__ float W2s[H1DIM * H2DIM];
  __shared__ float h1s[4][124];
  __shared__ float f2red[4];
  for (int e = t; e < H1DIM * H2DIM; e += 256) W2s[e] = W2[e];
  const int wv = t >> 6, lane = t & 63;
  const int n = blockIdx.x * 4 + wv;
  const int h = lane >> 4, o2 = (lane & 15) * 2;
  float tot0 = 0.f, tot1 = 0.f;
#pragma unroll
  for (int z = 0; z < 4; ++z) {
    const float* pp = part + ((size_t)(z * 4 + h) * NN + n) * 32 + o2;
    float2 u = *(const float2*)pp;
    tot0 += u.x;
    tot1 += u.y;
  }
  float l = __shfl(tot0, h * 16 + 15);
  float inv = 1.f / l;
  if (o2 < 30) {
    h1s[wv][h * 30 + o2] = lrelu(tot0 * inv + b1[h * 30 + o2]);
    h1s[wv][h * 30 + o2 + 1] = lrelu(tot1 * inv + b1[h * 30 + o2 + 1]);
  }
  __syncthreads();
  const int o = lane;
  float acc = 0.f;
  if (o < H2DIM) {
    const float* hr = h1s[wv];
#pragma unroll 4
    for (int k = 0; k < H1DIM; ++k) acc += hr[k] * W2s[k * H2DIM + o];
  }
  unsigned short wbv = (o < H2DIM) ? bfrne(acc) : (o == H2DIM ? (unsigned short)0x3f80 : (unsigned short)0);
  whbt2[(size_t)o * NNP + n] = wbv;
  float ps = (o < H2DIM) ? acc * a2s[o] : 0.f;
  float pd = (o < H2DIM) ? acc * a2d[o] : 0.f;
  for (int off = 32; off > 0; off >>= 1) {
    ps += __shfl_down(ps, off);
    pd += __shfl_down(pd, off);
  }
  if (lane == 0) {
    f1b[n] = ps;
    f2b[n] = pd;
    f2red[wv] = pd;
  }
  __syncthreads();
  if (t == 0) {
    float m = fmaxf(fmaxf(f2red[0], f2red[1]), fmaxf(f2red[2], f2red[3]));
    atomicMax(mxu2, fenc(m));
  }
}

// ---------------- MFMA attention layer 2: BI=128, LDS-staged B (shared across waves) ----------------
// grid (32 i-blocks, 8 j-split), block 256; each wave covers 32 i-rows (2 row-groups)
__global__ __launch_bounds__(256) void k_att2m(const unsigned short* __restrict__ whbt2,
                                               const float* __restrict__ f1b, const float* __restrict__ f2b,
                                               const unsigned* __restrict__ mxu2,
                                               const unsigned int* __restrict__ bits32,
                                               float* __restrict__ part) {
  const int js = blockIdx.y;
  const int t = threadIdx.x;
  const int lane = t & 63, wave = t >> 6;
  const int m = lane & 15, q = lane >> 4;
  const int i0w = blockIdx.x * 128 + wave * 32;
  const int jbase = js * 512;
  const float mx0 = fdec(mxu2[0]);
  __shared__ float2 es[512];
  __shared__ unsigned short bsm2[2][8192];
  for (int e = t; e < 512; e += 256) {
    float fv = f2b[jbase + e] - mx0;
    es[e] = make_float2(__expf(fv), __expf(0.1f * fv));
  }
  float Rr[2];
  const uint4* br[2];
#pragma unroll
  for (int rg = 0; rg < 2; ++rg) {
    const float f1r = f1b[i0w + rg * 16 + m];
    const float s = f1r + mx0;
    Rr[rg] = __expf(fminf(60.f, -0.9f * s));
    br[rg] = (const uint4*)(bits32 + (size_t)(i0w + rg * 16 + m) * BROW + (jbase >> 5));
  }
  const float2* fp = es;
  const int r2 = t >> 2;
  const int sw2 = (r2 & 3) ^ ((r2 >> 2) & 3);
  const unsigned short* gB2 = whbt2 + (size_t)r2 * NNP + jbase + ((t & 3) ^ sw2) * 8;
  f32x4 acc[2][4];
#pragma unroll
  for (int rg = 0; rg < 2; ++rg)
#pragma unroll
    for (int xx = 0; xx < 4; ++xx) acc[rg][xx] = (f32x4){0.f, 0.f, 0.f, 0.f};

  __syncthreads();  // es ready

#pragma unroll
  for (int c = 0; c < 4; ++c) GL16(gB2 + c * 32, &bsm2[0][c * 2048 + t * 8]);

#pragma unroll
  for (int jc = 0; jc < 4; ++jc) {
    const int cur = jc & 1;
    uint4 bqr[2];
    bqr[0] = br[0][jc];
    bqr[1] = br[1][jc];
    if (jc < 3) {
#pragma unroll
      for (int c = 0; c < 4; ++c) GL16(gB2 + (jc + 1) * 128 + c * 32, &bsm2[cur ^ 1][c * 2048 + t * 8]);
      asm volatile("s_waitcnt vmcnt(4)" ::: "memory");
    } else {
      asm volatile("s_waitcnt vmcnt(0)" ::: "memory");
    }
    __builtin_amdgcn_s_barrier();
    __builtin_amdgcn_sched_barrier(0);
#pragma unroll
    for (int sub = 0; sub < 4; ++sub) {
      const int jl = jc * 128 + sub * 32;
      float4 e01 = *(const float4*)(fp + jl + q * 8);
      float4 e23 = *(const float4*)(fp + jl + q * 8 + 2);
      float4 e45 = *(const float4*)(fp + jl + q * 8 + 4);
      float4 e67 = *(const float4*)(fp + jl + q * 8 + 6);
      const int p = sub * 4 + q;
#pragma unroll
      for (int rg = 0; rg < 2; ++rg) {
        const uint4 bq = bqr[rg];
        unsigned bsel = (sub == 0 ? bq.x : sub == 1 ? bq.y : sub == 2 ? bq.z : bq.w) >> (q * 8);
        const float R = Rr[rg];
        auto sc = [&](float ep, float en, int jj) {
          float wv = fmaxf(ep, R * en);
          return ((bsel >> jj) & 1u) ? wv : 0.f;
        };
        union { short8_t v; unsigned u[4]; } A;
        A.u[0] = bfpk(sc(e01.x, e01.y, 0), sc(e01.z, e01.w, 1));
        A.u[1] = bfpk(sc(e23.x, e23.y, 2), sc(e23.z, e23.w, 3));
        A.u[2] = bfpk(sc(e45.x, e45.y, 4), sc(e45.z, e45.w, 5));
        A.u[3] = bfpk(sc(e67.x, e67.y, 6), sc(e67.z, e67.w, 7));
#pragma unroll
        for (int tile = 0; tile < 4; ++tile) {
          const int f = tile * 16 + m;
          const int sw = (f & 3) ^ ((f >> 2) & 3);
          short8_t b = *(const short8_t*)&bsm2[cur][(p >> 2) * 2048 + f * 32 + (((p & 3) ^ sw)) * 8];
          acc[rg][tile] = __builtin_amdgcn_mfma_f32_16x16x32_bf16(A.v, b, acc[rg][tile], 0, 0, 0);
        }
      }
    }
    __builtin_amdgcn_sched_barrier(0);
    __builtin_amdgcn_s_barrier();
  }
#pragma unroll
  for (int rg = 0; rg < 2; ++rg) {
    float* pp = part + ((size_t)js * NN + i0w + rg * 16 + q * 4) * 64 + m;
#pragma unroll
    for (int tile = 0; tile < 4; ++tile)
#pragma unroll
      for (int r = 0; r < 4; ++r) pp[r * 64 + tile * 16] = acc[rg][tile][r];
  }
}

// ---------------- fused: h2 combine + FiLM + logits ----------------
// grid 1024, block 256 (4 waves = 4 nodes)
__global__ __launch_bounds__(256) void k_fuseB(const float* __restrict__ part, const float* __restrict__ b2,
                                               const float* __restrict__ l_loc,
                                               const float* __restrict__ Wl1, const float* __restrict__ bl1,
                                               const float* __restrict__ Wl2, const float* __restrict__ bl2,
                                               const float* __restrict__ Wg, const float* __restrict__ bg,
                                               const float* __restrict__ Wb, const float* __restrict__ bb,
                                               const float* __restrict__ Wgate, const float* __restrict__ bgate,
                                               const float* __restrict__ Wc, float* __restrict__ logits) {
  const int t = threadIdx.x;
  const int wv = t >> 6, lane = t & 63;
  const int n = blockIdx.x * 4 + wv;
  const float* p = part + (size_t)n * 64 + lane;
  float tot = 0.f;
#pragma unroll
  for (int z = 0; z < 8; ++z) tot += p[(size_t)z * NN * 64];
  float l = __shfl(tot, 50);
  float hv = (lane < H2DIM) ? lrelu(tot / l + b2[lane]) : 0.f;
  // FiLM
  int r32 = lane & 31;
  float locv = l_loc[n * 16 + (lane & 15)];
  float cov = __shfl(locv, 15);
  cov = fminf(fmaxf(cov, 0.f), 1.f);
  float a1v = bl1[r32];
#pragma unroll
  for (int j = 0; j < 16; ++j) a1v += Wl1[r32 * 16 + j] * __shfl(locv, j);
  float z1 = lrelu(a1v);
  float a2v = bl2[r32];
#pragma unroll
  for (int j = 0; j < 32; ++j) a2v += Wl2[r32 * 32 + j] * __shfl(z1, j);
  float z2 = lrelu(a2v);
  float gs = bgate[0];
  float gam, bet;
  {
    int o = lane < H2DIM ? lane : 0;
    gam = bg[o];
    bet = bb[o];
#pragma unroll
    for (int j = 0; j < 32; ++j) {
      float zj = __shfl(z2, j);
      gs += Wgate[j] * zj;
      gam += Wg[o * 32 + j] * zj;
      bet += Wb[o * 32 + j] * zj;
    }
  }
  float g = cov / (1.f + __expf(-gs));
  float hf = hv + g * (gam * hv + bet);
  int o = lane < H2DIM ? lane : 0;
  float p0 = lane < H2DIM ? hf * Wc[o] : 0.f;
  float p1 = lane < H2DIM ? hf * Wc[H2DIM + o] : 0.f;
  for (int off = 32; off > 0; off >>= 1) {
    p0 += __shfl_down(p0, off);
    p1 += __shfl_down(p1, off);
  }
  if (lane == 0) {
    logits[n * 2 + 0] = lrelu(p0);
    logits[n * 2 + 1] = lrelu(p1);
  }
}

// ---------------- MERGED SSDB: each block redundantly computes all 4 combo-sums, writes out-slice ----------------
// grid 33 x 256; wave wv handles combo wv: sum_k lrelu(Ws1[k]·logits[hemi,:,c] + bs1[k]) * Ws2[k]
__global__ __launch_bounds__(256) void k_fin(const float* __restrict__ logits,
                                             const float* __restrict__ Ws1, const float* __restrict__ bs1,
                                             const float* __restrict__ Ws2, const float* __restrict__ bs2,
                                             float* __restrict__ out) {
  __shared__ float Bs[4];
  const int t = threadIdx.x;
  const int wv = t >> 6, lane = t & 63;
  const int hemi = wv >> 1, c = wv & 1;
  const float* lc = logits + (size_t)hemi * 4096 + c;
  float total = 0.f;
  for (int k = 0; k < 60; ++k) {
    const float* wr = Ws1 + (size_t)k * 2048;
    float acc = 0.f;
#pragma unroll 4
    for (int i = lane; i < 2048; i += 64) acc += wr[i] * lc[2 * i];
    for (int off = 32; off > 0; off >>= 1) acc += __shfl_down(acc, off);
    if (lane == 0) total += lrelu(acc + bs1[k]) * Ws2[k];
  }
  if (lane == 0) Bs[wv] = lrelu(total + bs2[0]);
  __syncthreads();
  int id = blockIdx.x * 256 + t;
  if (id < 2 * NN) {
    int n = id >> 1, cc = id & 1;
    out[id] = logits[id] + Bs[(n < 2048 ? 0 : 2) + cc];
  } else if (id < 2 * NN + 2) {
    int cc = id - 2 * NN;
    out[id] = 0.5f * (Bs[cc] + Bs[2 + cc]);
  }
}

// ---------------- workspace layout (float offsets) ----------------
#define OFF_BITS 0          // 4096*66 u64 = 540672 f
#define OFF_W1T 540672      // 128*4128 shorts = 264192 f
#define OFF_GP 804864       // [8][4096][128] = 4194304 f; A1P/A2P overlay
#define OFF_A1P 804864      // [4][4][4096][32] = 2097152
#define OFF_A2P 804864      // [8][4096][64] = 2097152
#define OFF_WH1BT 4999168   // 128*4128 shorts = 264192 f
#define OFF_F1A 5263360     // [4][4096]
#define OFF_F2A 5279744     // [4][4096]
#define OFF_WH2BT 5296128   // 64*4128 shorts = 132096 f
#define OFF_F12 5428224     // 4096
#define OFF_F22 5432320     // 4096
#define OFF_LOG 5436416     // 8192
#define OFF_MX 5444608      // 8 uints: [0..3]=mxu1, [4]=mxu2

extern "C" void kernel_launch(void* const* d_in, const int* in_sizes, int n_in,
                              void* d_out, int out_size, void* d_ws, size_t ws_size,
                              hipStream_t stream) {
  const float* x_fc  = (const float*)d_in[0];
  const int*   adj   = (const int*)d_in[1];
  const float* l_loc = (const float*)d_in[2];
  const float* W1    = (const float*)d_in[3];
  const float* a1s   = (const float*)d_in[4];
  const float* a1d   = (const float*)d_in[5];
  const float* b1    = (const float*)d_in[6];
  const float* W2    = (const float*)d_in[7];
  const float* a2s   = (const float*)d_in[8];
  const float* a2d   = (const float*)d_in[9];
  const float* b2    = (const float*)d_in[10];
  const float* Wc    = (const float*)d_in[11];
  const float* Wl1   = (const float*)d_in[12];
  const float* bl1   = (const float*)d_in[13];
  const float* Wl2   = (const float*)d_in[14];
  const float* bl2   = (const float*)d_in[15];
  const float* Wg    = (const float*)d_in[16];
  const float* bg    = (const float*)d_in[17];
  const float* Wb    = (const float*)d_in[18];
  const float* bb    = (const float*)d_in[19];
  const float* Wgate = (const float*)d_in[20];
  const float* bgate = (const float*)d_in[21];
  const float* Ws1   = (const float*)d_in[22];
  const float* bs1   = (const float*)d_in[23];
  const float* Ws2   = (const float*)d_in[24];
  const float* bs2   = (const float*)d_in[25];
  float* out = (float*)d_out;
  float* w = (float*)d_ws;
  unsigned long long* bits = (unsigned long long*)(w + OFF_BITS);
  const unsigned int* bits32 = (const unsigned int*)bits;
  unsigned short* wh1bt = (unsigned short*)(w + OFF_WH1BT);
  unsigned short* wh2bt = (unsigned short*)(w + OFF_WH2BT);
  unsigned short* w1t = (unsigned short*)(w + OFF_W1T);
  unsigned* mxu = (unsigned*)(w + OFF_MX);

  k_pre<<<16, 256, 0, stream>>>(W1, a1s, a1d, w1t, mxu);
  k_gb<<<16640, 256, 0, stream>>>(x_fc, w1t, w + OFF_GP, adj, bits);
  k_f1c<<<256, 256, 0, stream>>>(w + OFF_GP, wh1bt, w + OFF_F1A, w + OFF_F2A, mxu);
  k_att1m<<<dim3(32, HEADS, 4), 256, 0, stream>>>(wh1bt, w + OFF_F1A, w + OFF_F2A,
                                                  mxu, bits32, w + OFF_A1P);
  k_fuseA<<<1024, 256, 0, stream>>>(w + OFF_A1P, b1, W2, a2s, a2d, wh2bt,
                                    w + OFF_F12, w + OFF_F22, mxu + 4);
  k_att2m<<<dim3(32, 8), 256, 0, stream>>>(wh2bt, w + OFF_F12, w + OFF_F22,
                                           mxu + 4, bits32, w + OFF_A2P);
  k_fuseB<<<1024, 256, 0, stream>>>(w + OFF_A2P, b2, l_loc, Wl1, bl1, Wl2, bl2,
                                    Wg, bg, Wb, bb, Wgate, bgate, Wc, w + OFF_LOG);
  k_fin<<<33, 256, 0, stream>>>(w + OFF_LOG, Ws1, bs1, Ws2, bs2, out);
}

// Round 12
// 300.166 us; speedup vs baseline: 1.6324x; 1.6324x over previous
//
#include <hip/hip_runtime.h>

#define NN 4096
#define NNP 4128   // padded row stride (shorts) to break 8KB channel aliasing
#define BROW 132   // bits row stride in u32 (528B, breaks 512B aliasing)
#define HEADS 4
#define H1PER 30
#define H1DIM 120
#define H2DIM 50

typedef short short8_t __attribute__((ext_vector_type(8)));
typedef float f32x4 __attribute__((ext_vector_type(4)));

__device__ __forceinline__ float lrelu(float x) { return x > 0.f ? x : 0.1f * x; }

__device__ __forceinline__ unsigned short bfrne(float x) {
  unsigned u = __float_as_uint(x);
  u += 0x7fffu + ((u >> 16) & 1u);
  return (unsigned short)(u >> 16);
}
__device__ __forceinline__ unsigned bfpk_rne(float lo, float hi) {
  return (unsigned)bfrne(lo) | ((unsigned)bfrne(hi) << 16);
}
__device__ __forceinline__ unsigned bfpk(float lo, float hi) {
  unsigned a = (__float_as_uint(lo) + 0x8000u) >> 16;
  unsigned b = (__float_as_uint(hi) + 0x8000u) & 0xffff0000u;
  return a | b;
}
// monotone float<->uint encoding for atomicMax-based float max
__device__ __forceinline__ unsigned fenc(float x) {
  unsigned u = __float_as_uint(x);
  return (u & 0x80000000u) ? ~u : (u | 0x80000000u);
}
__device__ __forceinline__ float fdec(unsigned u) {
  return (u & 0x80000000u) ? __uint_as_float(u ^ 0x80000000u) : __uint_as_float(~u);
}

#define GL16(g, l)                                                                        \
  __builtin_amdgcn_global_load_lds((const __attribute__((address_space(1))) unsigned int*)(g), \
                                   (__attribute__((address_space(3))) unsigned int*)(l), 16, 0, 0)

// ---------------- prep: W1 -> bf16 w1t[128][NNP] + f1/f2 features + mxu init ----------------
__global__ __launch_bounds__(256) void k_pre(const float* __restrict__ W1,
                                             const float* __restrict__ a1s,
                                             const float* __restrict__ a1d,
                                             unsigned short* __restrict__ w1t,
                                             unsigned* __restrict__ mxu) {
  int t = threadIdx.x;
  if (blockIdx.x == 0 && t < 8) mxu[t] = 0;  // encoded-domain minimum
  int k = blockIdx.x * 256 + t;
#pragma unroll
  for (int h = 0; h < 4; ++h) {
    const float* wp = W1 + ((size_t)h * 4096 + k) * H1PER;
    float fs = 0.f, fd = 0.f;
#pragma unroll
    for (int oo = 0; oo < H1PER; ++oo) {
      float v = wp[oo];
      w1t[(size_t)(h * 30 + oo) * NNP + k] = bfrne(v);
      fs += v * a1s[h * H1PER + oo];
      fd += v * a1d[h * H1PER + oo];
    }
    w1t[(size_t)(120 + h) * NNP + k] = bfrne(fs);
    w1t[(size_t)(124 + h) * NNP + k] = bfrne(fd);
  }
}

// ---------------- MERGED: MFMA GEMM1 (blocks 0..255) + adj->bits (blocks 256..16639) ----------------
// GEMM: BM=128, BK=32, double-buffered, counted vmcnt(6) (refcheck-proven body).
// Bits blocks are pure-BW and overlap gemm's latency stalls; bits output first read 2 dispatches later.
__global__ __launch_bounds__(256) void k_gb(const float* __restrict__ x,
                                            const unsigned short* __restrict__ w1t,
                                            float* __restrict__ part,
                                            const int* __restrict__ adj,
                                            unsigned long long* __restrict__ bits) {
  const int t = threadIdx.x;
  __shared__ float xs[2][128 * 32];            // A: 16 KB/buf
  __shared__ unsigned short bs[2][128 * 32];   // B: 8 KB/buf
  if (blockIdx.x >= 256) {
    // ---- bits path (no LDS use) ----
    int id = blockIdx.x - 256;
    int n = id >> 2, r = id & 3;
    size_t base = (size_t)n * 4096 + r * 1024;
    int v0 = adj[base + t];
    int v1 = adj[base + 256 + t];
    int v2 = adj[base + 512 + t];
    int v3 = adj[base + 768 + t];
    unsigned long long m0 = __ballot(v0 > 0);
    unsigned long long m1 = __ballot(v1 > 0);
    unsigned long long m2 = __ballot(v2 > 0);
    unsigned long long m3 = __ballot(v3 > 0);
    if ((t & 63) == 0) {
      size_t w = (size_t)n * (BROW / 2) + r * 16 + (t >> 6);
      bits[w] = m0;
      bits[w + 4] = m1;
      bits[w + 8] = m2;
      bits[w + 12] = m3;
    }
    return;
  }
  // ---- gemm path ----
  const int lane = t & 63, wave = t >> 6;
  const int m = lane & 15, q = lane >> 4;
  const int i0 = (blockIdx.x & 31) * 128;
  const int kz = (blockIdx.x >> 5) * 512;
  const int ar_ = t >> 3, ac_ = t & 7;
  const float* gxa = x + (size_t)(i0 + ar_) * 4096 + kz + ((ac_ ^ (ar_ & 7)) * 4);
  const int br_ = t >> 2;
  const int bsw = (br_ & 3) ^ ((br_ >> 2) & 3);
  const unsigned short* gwb = w1t + (size_t)br_ * NNP + kz + ((t & 3) ^ bsw) * 8;
  const int asw = m & 7;
  f32x4 acc[2][8];
#pragma unroll
  for (int rg = 0; rg < 2; ++rg)
#pragma unroll
    for (int nt = 0; nt < 8; ++nt) acc[rg][nt] = (f32x4){0.f, 0.f, 0.f, 0.f};

  auto STAGE = [&](int buf, int kk) {
#pragma unroll
    for (int i = 0; i < 4; ++i)
      GL16(gxa + (size_t)i * 32 * 4096 + kk, &xs[buf][(i * 32 + ar_) * 32 + ac_ * 4]);
#pragma unroll
    for (int i = 0; i < 2; ++i)
      GL16(gwb + (size_t)i * 64 * NNP + kk, &bs[buf][(i * 64 + br_) * 32 + (t & 3) * 8]);
  };

  STAGE(0, 0);  // prologue
#pragma unroll
  for (int it = 0; it < 16; ++it) {
    const int cur = it & 1;
    if (it < 15) {
      STAGE(cur ^ 1, (it + 1) * 32);
      asm volatile("s_waitcnt vmcnt(6)" ::: "memory");  // current step's 6 done; next 6 in flight
    } else {
      asm volatile("s_waitcnt vmcnt(0)" ::: "memory");
    }
    __builtin_amdgcn_s_barrier();
    __builtin_amdgcn_sched_barrier(0);
    const int c0 = q * 2;
    union { short8_t v; unsigned u[4]; } A[2];
#pragma unroll
    for (int rg = 0; rg < 2; ++rg) {
      const int arow = wave * 32 + rg * 16 + m;  // arow&7 == m&7
      float4 a0 = *(const float4*)&xs[cur][arow * 32 + ((c0 ^ asw) * 4)];
      float4 a1 = *(const float4*)&xs[cur][arow * 32 + (((c0 + 1) ^ asw) * 4)];
      A[rg].u[0] = bfpk_rne(a0.x, a0.y);
      A[rg].u[1] = bfpk_rne(a0.z, a0.w);
      A[rg].u[2] = bfpk_rne(a1.x, a1.y);
      A[rg].u[3] = bfpk_rne(a1.z, a1.w);
    }
#pragma unroll
    for (int nt = 0; nt < 8; ++nt) {
      const int f = nt * 16 + m;
      const int fsw = (f & 3) ^ ((f >> 2) & 3);
      short8_t B = *(const short8_t*)&bs[cur][f * 32 + ((q ^ fsw) * 8)];
      acc[0][nt] = __builtin_amdgcn_mfma_f32_16x16x32_bf16(A[0].v, B, acc[0][nt], 0, 0, 0);
      acc[1][nt] = __builtin_amdgcn_mfma_f32_16x16x32_bf16(A[1].v, B, acc[1][nt], 0, 0, 0);
    }
    __builtin_amdgcn_sched_barrier(0);
    __builtin_amdgcn_s_barrier();
  }
  float* pp = part + ((size_t)(blockIdx.x >> 5) * 4096 + i0 + wave * 32 + q * 4) * 128 + m;
#pragma unroll
  for (int rg = 0; rg < 2; ++rg)
#pragma unroll
    for (int nt = 0; nt < 8; ++nt)
#pragma unroll
      for (int r = 0; r < 4; ++r) pp[(rg * 16 + r) * 128 + nt * 16] = acc[rg][nt][r];
}

// ---------------- combine 8 k-split partials -> whbt(bf16,T) + f1/f2 + max1(atomic) ----------------
__global__ __launch_bounds__(256) void k_f1c(const float* __restrict__ part,
                                             unsigned short* __restrict__ whbt,
                                             float* __restrict__ f1, float* __restrict__ f2,
                                             unsigned* __restrict__ mxu1) {
  const int t = threadIdx.x;
  const int n = blockIdx.x * 16 + (t >> 4);
  const int og = (t & 15) * 8;
  __shared__ float f2loc[16][4];
  float s[8] = {0.f, 0.f, 0.f, 0.f, 0.f, 0.f, 0.f, 0.f};
  for (int z = 0; z < 8; ++z) {
    const float* pp = part + ((size_t)z * NN + n) * 128 + og;
    float4 u0 = *(const float4*)pp;
    float4 u1 = *(const float4*)(pp + 4);
    s[0] += u0.x; s[1] += u0.y; s[2] += u0.z; s[3] += u0.w;
    s[4] += u1.x; s[5] += u1.y; s[6] += u1.z; s[7] += u1.w;
  }
  if (og < 120) {
#pragma unroll
    for (int j = 0; j < 8; ++j) {
      int o = og + j;
      int h = o / 30, oo = o - h * 30;
      whbt[(size_t)(h * 32 + oo) * NNP + n] = bfrne(s[j]);
    }
  } else {
#pragma unroll
    for (int j = 0; j < 4; ++j) {
      f1[(size_t)j * NN + n] = s[j];
      f2[(size_t)j * NN + n] = s[4 + j];
      f2loc[t >> 4][j] = s[4 + j];
    }
  }
  if ((t & 15) < 8) {
    int h = (t & 15) >> 1, odd = (t & 15) & 1;
    whbt[(size_t)(h * 32 + 30 + odd) * NNP + n] = odd ? 0 : 0x3f80;
  }
  __syncthreads();
  if (t < 4) {
    float m = f2loc[0][t];
#pragma unroll
    for (int i = 1; i < 16; ++i) m = fmaxf(m, f2loc[i][t]);
    atomicMax(&mxu1[t], fenc(m));
  }
}

// ---------------- MFMA attention layer 1: BI=128, LDS-staged B (shared across waves) ----------------
// grid (32 i-blocks, 4 heads, 4 j-split), block 256; each wave covers 32 i-rows (2 row-groups)
__global__ __launch_bounds__(256) void k_att1m(const unsigned short* __restrict__ whbt,
                                               const float* __restrict__ f1, const float* __restrict__ f2,
                                               const unsigned* __restrict__ mxu1,
                                               const unsigned int* __restrict__ bits32,
                                               float* __restrict__ part) {
  const int h = blockIdx.y, js = blockIdx.z;
  const int t = threadIdx.x;
  const int lane = t & 63, wave = t >> 6;
  const int m = lane & 15, q = lane >> 4;
  const int i0w = blockIdx.x * 128 + wave * 32;
  const int jbase = js * 1024;
  const float mxh = fdec(mxu1[h]);
  __shared__ float2 es[1024];
  __shared__ unsigned short bsm1[2][8192];  // 2 x 16KB
  for (int e = t; e < 1024; e += 256) {
    float fv = f2[h * NN + jbase + e] - mxh;
    es[e] = make_float2(__expf(fv), __expf(0.1f * fv));
  }
  float Rr[2];
  const uint4* br[2];
#pragma unroll
  for (int rg = 0; rg < 2; ++rg) {
    const float f1r = f1[h * NN + i0w + rg * 16 + m];
    const float s = f1r + mxh;
    Rr[rg] = __expf(fminf(60.f, -0.9f * s));
    br[rg] = (const uint4*)(bits32 + (size_t)(i0w + rg * 16 + m) * BROW + (jbase >> 5));
  }
  const float2* fp = es;
  const int r_st = t >> 3;
  const unsigned short* gB = whbt + (size_t)(h * 32 + r_st) * NNP + jbase + ((t & 7) ^ (r_st & 7)) * 8;
  f32x4 acc[2][2];
#pragma unroll
  for (int rg = 0; rg < 2; ++rg) {
    acc[rg][0] = (f32x4){0.f, 0.f, 0.f, 0.f};
    acc[rg][1] = (f32x4){0.f, 0.f, 0.f, 0.f};
  }

  __syncthreads();  // es ready

#pragma unroll
  for (int c = 0; c < 4; ++c) GL16(gB + c * 64, &bsm1[0][c * 2048 + t * 8]);

#pragma unroll
  for (int jc = 0; jc < 4; ++jc) {
    const int cur = jc & 1;
    uint4 bqq[2][2];
#pragma unroll
    for (int rg = 0; rg < 2; ++rg) {
      bqq[rg][0] = br[rg][jc * 2];
      bqq[rg][1] = br[rg][jc * 2 + 1];
    }
    if (jc < 3) {
#pragma unroll
      for (int c = 0; c < 4; ++c) GL16(gB + (jc + 1) * 256 + c * 64, &bsm1[cur ^ 1][c * 2048 + t * 8]);
      asm volatile("s_waitcnt vmcnt(4)" ::: "memory");
    } else {
      asm volatile("s_waitcnt vmcnt(0)" ::: "memory");
    }
    __builtin_amdgcn_s_barrier();
    __builtin_amdgcn_sched_barrier(0);
#pragma unroll
    for (int g = 0; g < 2; ++g) {
#pragma unroll
      for (int sub = 0; sub < 4; ++sub) {
        const int jl = (jc * 2 + g) * 128 + sub * 32;
        float4 e01 = *(const float4*)(fp + jl + q * 8);
        float4 e23 = *(const float4*)(fp + jl + q * 8 + 2);
        float4 e45 = *(const float4*)(fp + jl + q * 8 + 4);
        float4 e67 = *(const float4*)(fp + jl + q * 8 + 6);
        const int p = g * 16 + sub * 4 + q;
        short8_t b0 = *(const short8_t*)&bsm1[cur][(p >> 3) * 2048 + m * 64 + ((p & 7) ^ (m & 7)) * 8];
        short8_t b1 = *(const short8_t*)&bsm1[cur][(p >> 3) * 2048 + (m + 16) * 64 + ((p & 7) ^ ((m + 16) & 7)) * 8];
#pragma unroll
        for (int rg = 0; rg < 2; ++rg) {
          const uint4 bq = bqq[rg][g];
          unsigned bsel = (sub == 0 ? bq.x : sub == 1 ? bq.y : sub == 2 ? bq.z : bq.w) >> (q * 8);
          const float R = Rr[rg];
          auto sc = [&](float ep, float en, int jj) {
            float wv = fmaxf(ep, R * en);
            return ((bsel >> jj) & 1u) ? wv : 0.f;
          };
          union { short8_t v; unsigned u[4]; } A;
          A.u[0] = bfpk(sc(e01.x, e01.y, 0), sc(e01.z, e01.w, 1));
          A.u[1] = bfpk(sc(e23.x, e23.y, 2), sc(e23.z, e23.w, 3));
          A.u[2] = bfpk(sc(e45.x, e45.y, 4), sc(e45.z, e45.w, 5));
          A.u[3] = bfpk(sc(e67.x, e67.y, 6), sc(e67.z, e67.w, 7));
          acc[rg][0] = __builtin_amdgcn_mfma_f32_16x16x32_bf16(A.v, b0, acc[rg][0], 0, 0, 0);
          acc[rg][1] = __builtin_amdgcn_mfma_f32_16x16x32_bf16(A.v, b1, acc[rg][1], 0, 0, 0);
        }
      }
    }
    __builtin_amdgcn_sched_barrier(0);
    __builtin_amdgcn_s_barrier();
  }
#pragma unroll
  for (int rg = 0; rg < 2; ++rg) {
    float* pp = part + ((size_t)(js * 4 + h) * NN + i0w + rg * 16 + q * 4) * 32 + m;
#pragma unroll
    for (int r = 0; r < 4; ++r) {
      pp[r * 32] = acc[rg][0][r];
      pp[r * 32 + 16] = acc[rg][1][r];
    }
  }
}

// ---------------- fused: h1 combine + GEMM2 + f2/whbt2 + max2 ----------------
// grid 1024, block 256 (4 waves = 4 nodes)
__global__ __launch_bounds__(256) void k_fuseA(const float* __restrict__ part, const float* __restrict__ b1,
                                               const float* __restrict__ W2, const float* __restrict__ a2s,
                                               const float* __restrict__ a2d,
                                               unsigned short* __restrict__ whbt2,
                                               float* __restrict__ f1b, float* __restrict__ f2b,
                                               unsigned* __restrict__ mxu2) {
  const int t = threadIdx.x;
  __shared__ float W2s[H1DIM * H2DIM];
  __shared__ float h1s[4][124];
  __shared__ float f2red[4];
  for (int e = t; e < H1DIM * H2DIM; e += 256) W2s[e] = W2[e];
  const int wv = t >> 6, lane = t & 63;
  const int n = blockIdx.x * 4 + wv;
  const int h = lane >> 4, o2 = (lane & 15) * 2;
  float tot0 = 0.f, tot1 = 0.f;
#pragma unroll
  for (int z = 0; z < 4; ++z) {
    const float* pp = part + ((size_t)(z * 4 + h) * NN + n) * 32 + o2;
    float2 u = *(const float2*)pp;
    tot0 += u.x;
    tot1 += u.y;
  }
  float l = __shfl(tot0, h * 16 + 15);
  float inv = 1.f / l;
  if (o2 < 30) {
    h1s[wv][h * 30 + o2] = lrelu(tot0 * inv + b1[h * 30 + o2]);
    h1s[wv][h * 30 + o2 + 1] = lrelu(tot1 * inv + b1[h * 30 + o2 + 1]);
  }
  __syncthreads();
  const int o = lane;
  float acc = 0.f;
  if (o < H2DIM) {
    const float* hr = h1s[wv];
#pragma unroll 4
    for (int k = 0; k < H1DIM; ++k) acc += hr[k] * W2s[k * H2DIM + o];
  }
  unsigned short wbv = (o < H2DIM) ? bfrne(acc) : (o == H2DIM ? (unsigned short)0x3f80 : (unsigned short)0);
  whbt2[(size_t)o * NNP + n] = wbv;
  float ps = (o < H2DIM) ? acc * a2s[o] : 0.f;
  float pd = (o < H2DIM) ? acc * a2d[o] : 0.f;
  for (int off = 32; off > 0; off >>= 1) {
    ps += __shfl_down(ps, off);
    pd += __shfl_down(pd, off);
  }
  if (lane == 0) {
    f1b[n] = ps;
    f2b[n] = pd;
    f2red[wv] = pd;
  }
  __syncthreads();
  if (t == 0) {
    float m = fmaxf(fmaxf(f2red[0], f2red[1]), fmaxf(f2red[2], f2red[3]));
    atomicMax(mxu2, fenc(m));
  }
}

// ---------------- MFMA attention layer 2: BI=128, LDS-staged B (shared across waves) ----------------
// grid (32 i-blocks, 8 j-split), block 256; each wave covers 32 i-rows (2 row-groups)
__global__ __launch_bounds__(256) void k_att2m(const unsigned short* __restrict__ whbt2,
                                               const float* __restrict__ f1b, const float* __restrict__ f2b,
                                               const unsigned* __restrict__ mxu2,
                                               const unsigned int* __restrict__ bits32,
                                               float* __restrict__ part) {
  const int js = blockIdx.y;
  const int t = threadIdx.x;
  const int lane = t & 63, wave = t >> 6;
  const int m = lane & 15, q = lane >> 4;
  const int i0w = blockIdx.x * 128 + wave * 32;
  const int jbase = js * 512;
  const float mx0 = fdec(mxu2[0]);
  __shared__ float2 es[512];
  __shared__ unsigned short bsm2[2][8192];
  for (int e = t; e < 512; e += 256) {
    float fv = f2b[jbase + e] - mx0;
    es[e] = make_float2(__expf(fv), __expf(0.1f * fv));
  }
  float Rr[2];
  const uint4* br[2];
#pragma unroll
  for (int rg = 0; rg < 2; ++rg) {
    const float f1r = f1b[i0w + rg * 16 + m];
    const float s = f1r + mx0;
    Rr[rg] = __expf(fminf(60.f, -0.9f * s));
    br[rg] = (const uint4*)(bits32 + (size_t)(i0w + rg * 16 + m) * BROW + (jbase >> 5));
  }
  const float2* fp = es;
  const int r2 = t >> 2;
  const int sw2 = (r2 & 3) ^ ((r2 >> 2) & 3);
  const unsigned short* gB2 = whbt2 + (size_t)r2 * NNP + jbase + ((t & 3) ^ sw2) * 8;
  f32x4 acc[2][4];
#pragma unroll
  for (int rg = 0; rg < 2; ++rg)
#pragma unroll
    for (int xx = 0; xx < 4; ++xx) acc[rg][xx] = (f32x4){0.f, 0.f, 0.f, 0.f};

  __syncthreads();  // es ready

#pragma unroll
  for (int c = 0; c < 4; ++c) GL16(gB2 + c * 32, &bsm2[0][c * 2048 + t * 8]);

#pragma unroll
  for (int jc = 0; jc < 4; ++jc) {
    const int cur = jc & 1;
    uint4 bqr[2];
    bqr[0] = br[0][jc];
    bqr[1] = br[1][jc];
    if (jc < 3) {
#pragma unroll
      for (int c = 0; c < 4; ++c) GL16(gB2 + (jc + 1) * 128 + c * 32, &bsm2[cur ^ 1][c * 2048 + t * 8]);
      asm volatile("s_waitcnt vmcnt(4)" ::: "memory");
    } else {
      asm volatile("s_waitcnt vmcnt(0)" ::: "memory");
    }
    __builtin_amdgcn_s_barrier();
    __builtin_amdgcn_sched_barrier(0);
#pragma unroll
    for (int sub = 0; sub < 4; ++sub) {
      const int jl = jc * 128 + sub * 32;
      float4 e01 = *(const float4*)(fp + jl + q * 8);
      float4 e23 = *(const float4*)(fp + jl + q * 8 + 2);
      float4 e45 = *(const float4*)(fp + jl + q * 8 + 4);
      float4 e67 = *(const float4*)(fp + jl + q * 8 + 6);
      const int p = sub * 4 + q;
#pragma unroll
      for (int rg = 0; rg < 2; ++rg) {
        const uint4 bq = bqr[rg];
        unsigned bsel = (sub == 0 ? bq.x : sub == 1 ? bq.y : sub == 2 ? bq.z : bq.w) >> (q * 8);
        const float R = Rr[rg];
        auto sc = [&](float ep, float en, int jj) {
          float wv = fmaxf(ep, R * en);
          return ((bsel >> jj) & 1u) ? wv : 0.f;
        };
        union { short8_t v; unsigned u[4]; } A;
        A.u[0] = bfpk(sc(e01.x, e01.y, 0), sc(e01.z, e01.w, 1));
        A.u[1] = bfpk(sc(e23.x, e23.y, 2), sc(e23.z, e23.w, 3));
        A.u[2] = bfpk(sc(e45.x, e45.y, 4), sc(e45.z, e45.w, 5));
        A.u[3] = bfpk(sc(e67.x, e67.y, 6), sc(e67.z, e67.w, 7));
#pragma unroll
        for (int tile = 0; tile < 4; ++tile) {
          const int f = tile * 16 + m;
          const int sw = (f & 3) ^ ((f >> 2) & 3);
          short8_t b = *(const short8_t*)&bsm2[cur][(p >> 2) * 2048 + f * 32 + (((p & 3) ^ sw)) * 8];
          acc[rg][tile] = __builtin_amdgcn_mfma_f32_16x16x32_bf16(A.v, b, acc[rg][tile], 0, 0, 0);
        }
      }
    }
    __builtin_amdgcn_sched_barrier(0);
    __builtin_amdgcn_s_barrier();
  }
#pragma unroll
  for (int rg = 0; rg < 2; ++rg) {
    float* pp = part + ((size_t)js * NN + i0w + rg * 16 + q * 4) * 64 + m;
#pragma unroll
    for (int tile = 0; tile < 4; ++tile)
#pragma unroll
      for (int r = 0; r < 4; ++r) pp[r * 64 + tile * 16] = acc[rg][tile][r];
  }
}

// ---------------- fused: h2 combine + FiLM + logits ----------------
// grid 1024, block 256 (4 waves = 4 nodes)
__global__ __launch_bounds__(256) void k_fuseB(const float* __restrict__ part, const float* __restrict__ b2,
                                               const float* __restrict__ l_loc,
                                               const float* __restrict__ Wl1, const float* __restrict__ bl1,
                                               const float* __restrict__ Wl2, const float* __restrict__ bl2,
                                               const float* __restrict__ Wg, const float* __restrict__ bg,
                                               const float* __restrict__ Wb, const float* __restrict__ bb,
                                               const float* __restrict__ Wgate, const float* __restrict__ bgate,
                                               const float* __restrict__ Wc, float* __restrict__ logits) {
  const int t = threadIdx.x;
  const int wv = t >> 6, lane = t & 63;
  const int n = blockIdx.x * 4 + wv;
  const float* p = part + (size_t)n * 64 + lane;
  float tot = 0.f;
#pragma unroll
  for (int z = 0; z < 8; ++z) tot += p[(size_t)z * NN * 64];
  float l = __shfl(tot, 50);
  float hv = (lane < H2DIM) ? lrelu(tot / l + b2[lane]) : 0.f;
  // FiLM
  int r32 = lane & 31;
  float locv = l_loc[n * 16 + (lane & 15)];
  float cov = __shfl(locv, 15);
  cov = fminf(fmaxf(cov, 0.f), 1.f);
  float a1v = bl1[r32];
#pragma unroll
  for (int j = 0; j < 16; ++j) a1v += Wl1[r32 * 16 + j] * __shfl(locv, j);
  float z1 = lrelu(a1v);
  float a2v = bl2[r32];
#pragma unroll
  for (int j = 0; j < 32; ++j) a2v += Wl2[r32 * 32 + j] * __shfl(z1, j);
  float z2 = lrelu(a2v);
  float gs = bgate[0];
  float gam, bet;
  {
    int o = lane < H2DIM ? lane : 0;
    gam = bg[o];
    bet = bb[o];
#pragma unroll
    for (int j = 0; j < 32; ++j) {
      float zj = __shfl(z2, j);
      gs += Wgate[j] * zj;
      gam += Wg[o * 32 + j] * zj;
      bet += Wb[o * 32 + j] * zj;
    }
  }
  float g = cov / (1.f + __expf(-gs));
  float hf = hv + g * (gam * hv + bet);
  int o = lane < H2DIM ? lane : 0;
  float p0 = lane < H2DIM ? hf * Wc[o] : 0.f;
  float p1 = lane < H2DIM ? hf * Wc[H2DIM + o] : 0.f;
  for (int off = 32; off > 0; off >>= 1) {
    p0 += __shfl_down(p0, off);
    p1 += __shfl_down(p1, off);
  }
  if (lane == 0) {
    logits[n * 2 + 0] = lrelu(p0);
    logits[n * 2 + 1] = lrelu(p1);
  }
}

// ---------------- SSDB stage A: 240 parallel dot-products (no atomics) ----------------
// grid (60 k, 4 combos), block 64: hsum[combo*60+k] = lrelu(dot + bs1[k]) * Ws2[k]
__global__ __launch_bounds__(64) void k_ssdbA(const float* __restrict__ logits,
                                              const float* __restrict__ Ws1, const float* __restrict__ bs1,
                                              const float* __restrict__ Ws2, float* __restrict__ hsum) {
  const int k = blockIdx.x, combo = blockIdx.y;
  const int hemi = combo >> 1, c = combo & 1;
  const int lane = threadIdx.x;
  const float* wr = Ws1 + (size_t)k * 2048;
  const float* lc = logits + (size_t)hemi * 4096 + c;
  float acc = 0.f;
#pragma unroll 4
  for (int i = lane; i < 2048; i += 64) acc += wr[i] * lc[2 * i];
  for (int off = 32; off > 0; off >>= 1) acc += __shfl_down(acc, off);
  if (lane == 0) hsum[combo * 60 + k] = lrelu(acc + bs1[k]) * Ws2[k];
}

// ---------------- SSDB stage B + final output ----------------
// grid 33 x 256: each block redundantly reduces hsum -> Bs[4], writes its out-slice
__global__ __launch_bounds__(256) void k_finB(const float* __restrict__ hsum,
                                              const float* __restrict__ bs2,
                                              const float* __restrict__ logits,
                                              float* __restrict__ out) {
  __shared__ float Bs[4];
  const int t = threadIdx.x;
  {
    int combo = t >> 6, k = t & 63;
    float v = (k < 60) ? hsum[combo * 60 + k] : 0.f;
    for (int off = 32; off > 0; off >>= 1) v += __shfl_down(v, off);
    if (k == 0) Bs[combo] = lrelu(v + bs2[0]);
  }
  __syncthreads();
  int id = blockIdx.x * 256 + t;
  if (id < 2 * NN) {
    int n = id >> 1, c = id & 1;
    out[id] = logits[id] + Bs[(n < 2048 ? 0 : 2) + c];
  } else if (id < 2 * NN + 2) {
    int c = id - 2 * NN;
    out[id] = 0.5f * (Bs[c] + Bs[2 + c]);
  }
}

// ---------------- workspace layout (float offsets) ----------------
#define OFF_BITS 0          // 4096*66 u64 = 540672 f
#define OFF_W1T 540672      // 128*4128 shorts = 264192 f
#define OFF_GP 804864       // [8][4096][128] = 4194304 f; A1P/A2P overlay
#define OFF_A1P 804864      // [4][4][4096][32] = 2097152
#define OFF_A2P 804864      // [8][4096][64] = 2097152
#define OFF_WH1BT 4999168   // 128*4128 shorts = 264192 f
#define OFF_F1A 5263360     // [4][4096]
#define OFF_F2A 5279744     // [4][4096]
#define OFF_WH2BT 5296128   // 64*4128 shorts = 132096 f
#define OFF_F12 5428224     // 4096
#define OFF_F22 5432320     // 4096
#define OFF_LOG 5436416     // 8192
#define OFF_MX 5444608      // 8 uints: [0..3]=mxu1, [4]=mxu2
#define OFF_HS 5444672      // 240 floats (ssdb hsum)

extern "C" void kernel_launch(void* const* d_in, const int* in_sizes, int n_in,
                              void* d_out, int out_size, void* d_ws, size_t ws_size,
                              hipStream_t stream) {
  const float* x_fc  = (const float*)d_in[0];
  const int*   adj   = (const int*)d_in[1];
  const float* l_loc = (const float*)d_in[2];
  const float* W1    = (const float*)d_in[3];
  const float* a1s   = (const float*)d_in[4];
  const float* a1d   = (const float*)d_in[5];
  const float* b1    = (const float*)d_in[6];
  const float* W2    = (const float*)d_in[7];
  const float* a2s   = (const float*)d_in[8];
  const float* a2d   = (const float*)d_in[9];
  const float* b2    = (const float*)d_in[10];
  const float* Wc    = (const float*)d_in[11];
  const float* Wl1   = (const float*)d_in[12];
  const float* bl1   = (const float*)d_in[13];
  const float* Wl2   = (const float*)d_in[14];
  const float* bl2   = (const float*)d_in[15];
  const float* Wg    = (const float*)d_in[16];
  const float* bg    = (const float*)d_in[17];
  const float* Wb    = (const float*)d_in[18];
  const float* bb    = (const float*)d_in[19];
  const float* Wgate = (const float*)d_in[20];
  const float* bgate = (const float*)d_in[21];
  const float* Ws1   = (const float*)d_in[22];
  const float* bs1   = (const float*)d_in[23];
  const float* Ws2   = (const float*)d_in[24];
  const float* bs2   = (const float*)d_in[25];
  float* out = (float*)d_out;
  float* w = (float*)d_ws;
  unsigned long long* bits = (unsigned long long*)(w + OFF_BITS);
  const unsigned int* bits32 = (const unsigned int*)bits;
  unsigned short* wh1bt = (unsigned short*)(w + OFF_WH1BT);
  unsigned short* wh2bt = (unsigned short*)(w + OFF_WH2BT);
  unsigned short* w1t = (unsigned short*)(w + OFF_W1T);
  unsigned* mxu = (unsigned*)(w + OFF_MX);

  k_pre<<<16, 256, 0, stream>>>(W1, a1s, a1d, w1t, mxu);
  k_gb<<<16640, 256, 0, stream>>>(x_fc, w1t, w + OFF_GP, adj, bits);
  k_f1c<<<256, 256, 0, stream>>>(w + OFF_GP, wh1bt, w + OFF_F1A, w + OFF_F2A, mxu);
  k_att1m<<<dim3(32, HEADS, 4), 256, 0, stream>>>(wh1bt, w + OFF_F1A, w + OFF_F2A,
                                                  mxu, bits32, w + OFF_A1P);
  k_fuseA<<<1024, 256, 0, stream>>>(w + OFF_A1P, b1, W2, a2s, a2d, wh2bt,
                                    w + OFF_F12, w + OFF_F22, mxu + 4);
  k_att2m<<<dim3(32, 8), 256, 0, stream>>>(wh2bt, w + OFF_F12, w + OFF_F22,
                                           mxu + 4, bits32, w + OFF_A2P);
  k_fuseB<<<1024, 256, 0, stream>>>(w + OFF_A2P, b2, l_loc, Wl1, bl1, Wl2, bl2,
                                    Wg, bg, Wb, bb, Wgate, bgate, Wc, w + OFF_LOG);
  k_ssdbA<<<dim3(60, 4), 64, 0, stream>>>(w + OFF_LOG, Ws1, bs1, Ws2, w + OFF_HS);
  k_finB<<<33, 256, 0, stream>>>(w + OFF_HS, bs2, w + OFF_LOG, out);
}

// Round 13
// 299.442 us; speedup vs baseline: 1.6363x; 1.0024x over previous
//
#include <hip/hip_runtime.h>

#define NN 4096
#define NNP 4128   // padded row stride (shorts) to break 8KB channel aliasing
#define BROW 132   // bits row stride in u32 (528B, breaks 512B aliasing)
#define HEADS 4
#define H1PER 30
#define H1DIM 120
#define H2DIM 50

typedef short short8_t __attribute__((ext_vector_type(8)));
typedef float f32x4 __attribute__((ext_vector_type(4)));

__device__ __forceinline__ float lrelu(float x) { return x > 0.f ? x : 0.1f * x; }

__device__ __forceinline__ unsigned short bfrne(float x) {
  unsigned u = __float_as_uint(x);
  u += 0x7fffu + ((u >> 16) & 1u);
  return (unsigned short)(u >> 16);
}
__device__ __forceinline__ unsigned bfpk_rne(float lo, float hi) {
  return (unsigned)bfrne(lo) | ((unsigned)bfrne(hi) << 16);
}
__device__ __forceinline__ unsigned bfpk(float lo, float hi) {
  unsigned a = (__float_as_uint(lo) + 0x8000u) >> 16;
  unsigned b = (__float_as_uint(hi) + 0x8000u) & 0xffff0000u;
  return a | b;
}
// monotone float<->uint encoding for atomicMax-based float max
__device__ __forceinline__ unsigned fenc(float x) {
  unsigned u = __float_as_uint(x);
  return (u & 0x80000000u) ? ~u : (u | 0x80000000u);
}
__device__ __forceinline__ float fdec(unsigned u) {
  return (u & 0x80000000u) ? __uint_as_float(u ^ 0x80000000u) : __uint_as_float(~u);
}

#define GL16(g, l)                                                                        \
  __builtin_amdgcn_global_load_lds((const __attribute__((address_space(1))) unsigned int*)(g), \
                                   (__attribute__((address_space(3))) unsigned int*)(l), 16, 0, 0)

// ---------------- prep: W1 -> bf16 w1t[128][NNP] + f1/f2 features + mxu init ----------------
__global__ __launch_bounds__(256) void k_pre(const float* __restrict__ W1,
                                             const float* __restrict__ a1s,
                                             const float* __restrict__ a1d,
                                             unsigned short* __restrict__ w1t,
                                             unsigned* __restrict__ mxu) {
  int t = threadIdx.x;
  if (blockIdx.x == 0 && t < 8) mxu[t] = 0;  // encoded-domain minimum
  int k = blockIdx.x * 256 + t;
#pragma unroll
  for (int h = 0; h < 4; ++h) {
    const float* wp = W1 + ((size_t)h * 4096 + k) * H1PER;
    float fs = 0.f, fd = 0.f;
#pragma unroll
    for (int oo = 0; oo < H1PER; ++oo) {
      float v = wp[oo];
      w1t[(size_t)(h * 30 + oo) * NNP + k] = bfrne(v);
      fs += v * a1s[h * H1PER + oo];
      fd += v * a1d[h * H1PER + oo];
    }
    w1t[(size_t)(120 + h) * NNP + k] = bfrne(fs);
    w1t[(size_t)(124 + h) * NNP + k] = bfrne(fd);
  }
}

// ---------------- MERGED: MFMA GEMM1 (blocks 0..511, 16 k-splits) + adj->bits (512..16895) ----------------
// GEMM: BM=128, BK=32, 16 k-splits (512 blocks -> 3 blocks/CU co-resident), double-buffered,
// counted vmcnt(6). Combines the three individually-validated wins: dbuf+vmcnt, halved B-bytes, 512-block grid.
__global__ __launch_bounds__(256) void k_gb(const float* __restrict__ x,
                                            const unsigned short* __restrict__ w1t,
                                            float* __restrict__ part,
                                            const int* __restrict__ adj,
                                            unsigned long long* __restrict__ bits) {
  const int t = threadIdx.x;
  __shared__ float xs[2][128 * 32];            // A: 16 KB/buf
  __shared__ unsigned short bs[2][128 * 32];   // B: 8 KB/buf
  if (blockIdx.x >= 512) {
    // ---- bits path (no LDS use) ----
    int id = blockIdx.x - 512;
    int n = id >> 2, r = id & 3;
    size_t base = (size_t)n * 4096 + r * 1024;
    int v0 = adj[base + t];
    int v1 = adj[base + 256 + t];
    int v2 = adj[base + 512 + t];
    int v3 = adj[base + 768 + t];
    unsigned long long m0 = __ballot(v0 > 0);
    unsigned long long m1 = __ballot(v1 > 0);
    unsigned long long m2 = __ballot(v2 > 0);
    unsigned long long m3 = __ballot(v3 > 0);
    if ((t & 63) == 0) {
      size_t w = (size_t)n * (BROW / 2) + r * 16 + (t >> 6);
      bits[w] = m0;
      bits[w + 4] = m1;
      bits[w + 8] = m2;
      bits[w + 12] = m3;
    }
    return;
  }
  // ---- gemm path ----
  const int lane = t & 63, wave = t >> 6;
  const int m = lane & 15, q = lane >> 4;
  const int i0 = (blockIdx.x & 31) * 128;
  const int kz = (blockIdx.x >> 5) * 256;   // 16 k-splits of 256
  const int ar_ = t >> 3, ac_ = t & 7;
  const float* gxa = x + (size_t)(i0 + ar_) * 4096 + kz + ((ac_ ^ (ar_ & 7)) * 4);
  const int br_ = t >> 2;
  const int bsw = (br_ & 3) ^ ((br_ >> 2) & 3);
  const unsigned short* gwb = w1t + (size_t)br_ * NNP + kz + ((t & 3) ^ bsw) * 8;
  const int asw = m & 7;
  f32x4 acc[2][8];
#pragma unroll
  for (int rg = 0; rg < 2; ++rg)
#pragma unroll
    for (int nt = 0; nt < 8; ++nt) acc[rg][nt] = (f32x4){0.f, 0.f, 0.f, 0.f};

  auto STAGE = [&](int buf, int kk) {
#pragma unroll
    for (int i = 0; i < 4; ++i)
      GL16(gxa + (size_t)i * 32 * 4096 + kk, &xs[buf][(i * 32 + ar_) * 32 + ac_ * 4]);
#pragma unroll
    for (int i = 0; i < 2; ++i)
      GL16(gwb + (size_t)i * 64 * NNP + kk, &bs[buf][(i * 64 + br_) * 32 + (t & 3) * 8]);
  };

  STAGE(0, 0);  // prologue
#pragma unroll
  for (int it = 0; it < 8; ++it) {
    const int cur = it & 1;
    if (it < 7) {
      STAGE(cur ^ 1, (it + 1) * 32);
      asm volatile("s_waitcnt vmcnt(6)" ::: "memory");  // current step's 6 done; next 6 in flight
    } else {
      asm volatile("s_waitcnt vmcnt(0)" ::: "memory");
    }
    __builtin_amdgcn_s_barrier();
    __builtin_amdgcn_sched_barrier(0);
    const int c0 = q * 2;
    union { short8_t v; unsigned u[4]; } A[2];
#pragma unroll
    for (int rg = 0; rg < 2; ++rg) {
      const int arow = wave * 32 + rg * 16 + m;  // arow&7 == m&7
      float4 a0 = *(const float4*)&xs[cur][arow * 32 + ((c0 ^ asw) * 4)];
      float4 a1 = *(const float4*)&xs[cur][arow * 32 + (((c0 + 1) ^ asw) * 4)];
      A[rg].u[0] = bfpk_rne(a0.x, a0.y);
      A[rg].u[1] = bfpk_rne(a0.z, a0.w);
      A[rg].u[2] = bfpk_rne(a1.x, a1.y);
      A[rg].u[3] = bfpk_rne(a1.z, a1.w);
    }
#pragma unroll
    for (int nt = 0; nt < 8; ++nt) {
      const int f = nt * 16 + m;
      const int fsw = (f & 3) ^ ((f >> 2) & 3);
      short8_t B = *(const short8_t*)&bs[cur][f * 32 + ((q ^ fsw) * 8)];
      acc[0][nt] = __builtin_amdgcn_mfma_f32_16x16x32_bf16(A[0].v, B, acc[0][nt], 0, 0, 0);
      acc[1][nt] = __builtin_amdgcn_mfma_f32_16x16x32_bf16(A[1].v, B, acc[1][nt], 0, 0, 0);
    }
    __builtin_amdgcn_sched_barrier(0);
    __builtin_amdgcn_s_barrier();
  }
  float* pp = part + ((size_t)(blockIdx.x >> 5) * 4096 + i0 + wave * 32 + q * 4) * 128 + m;
#pragma unroll
  for (int rg = 0; rg < 2; ++rg)
#pragma unroll
    for (int nt = 0; nt < 8; ++nt)
#pragma unroll
      for (int r = 0; r < 4; ++r) pp[(rg * 16 + r) * 128 + nt * 16] = acc[rg][nt][r];
}

// ---------------- combine 16 k-split partials -> whbt(bf16,T) + f1/f2 + max1(atomic) ----------------
__global__ __launch_bounds__(256) void k_f1c(const float* __restrict__ part,
                                             unsigned short* __restrict__ whbt,
                                             float* __restrict__ f1, float* __restrict__ f2,
                                             unsigned* __restrict__ mxu1) {
  const int t = threadIdx.x;
  const int n = blockIdx.x * 16 + (t >> 4);
  const int og = (t & 15) * 8;
  __shared__ float f2loc[16][4];
  float s[8] = {0.f, 0.f, 0.f, 0.f, 0.f, 0.f, 0.f, 0.f};
  for (int z = 0; z < 16; ++z) {
    const float* pp = part + ((size_t)z * NN + n) * 128 + og;
    float4 u0 = *(const float4*)pp;
    float4 u1 = *(const float4*)(pp + 4);
    s[0] += u0.x; s[1] += u0.y; s[2] += u0.z; s[3] += u0.w;
    s[4] += u1.x; s[5] += u1.y; s[6] += u1.z; s[7] += u1.w;
  }
  if (og < 120) {
#pragma unroll
    for (int j = 0; j < 8; ++j) {
      int o = og + j;
      int h = o / 30, oo = o - h * 30;
      whbt[(size_t)(h * 32 + oo) * NNP + n] = bfrne(s[j]);
    }
  } else {
#pragma unroll
    for (int j = 0; j < 4; ++j) {
      f1[(size_t)j * NN + n] = s[j];
      f2[(size_t)j * NN + n] = s[4 + j];
      f2loc[t >> 4][j] = s[4 + j];
    }
  }
  if ((t & 15) < 8) {
    int h = (t & 15) >> 1, odd = (t & 15) & 1;
    whbt[(size_t)(h * 32 + 30 + odd) * NNP + n] = odd ? 0 : 0x3f80;
  }
  __syncthreads();
  if (t < 4) {
    float m = f2loc[0][t];
#pragma unroll
    for (int i = 1; i < 16; ++i) m = fmaxf(m, f2loc[i][t]);
    atomicMax(&mxu1[t], fenc(m));
  }
}

// ---------------- MFMA attention layer 1: BI=128, LDS-staged B (shared across waves) ----------------
// grid (32 i-blocks, 4 heads, 4 j-split), block 256; each wave covers 32 i-rows (2 row-groups)
__global__ __launch_bounds__(256) void k_att1m(const unsigned short* __restrict__ whbt,
                                               const float* __restrict__ f1, const float* __restrict__ f2,
                                               const unsigned* __restrict__ mxu1,
                                               const unsigned int* __restrict__ bits32,
                                               float* __restrict__ part) {
  const int h = blockIdx.y, js = blockIdx.z;
  const int t = threadIdx.x;
  const int lane = t & 63, wave = t >> 6;
  const int m = lane & 15, q = lane >> 4;
  const int i0w = blockIdx.x * 128 + wave * 32;
  const int jbase = js * 1024;
  const float mxh = fdec(mxu1[h]);
  __shared__ float2 es[1024];
  __shared__ unsigned short bsm1[2][8192];  // 2 x 16KB
  for (int e = t; e < 1024; e += 256) {
    float fv = f2[h * NN + jbase + e] - mxh;
    es[e] = make_float2(__expf(fv), __expf(0.1f * fv));
  }
  float Rr[2];
  const uint4* br[2];
#pragma unroll
  for (int rg = 0; rg < 2; ++rg) {
    const float f1r = f1[h * NN + i0w + rg * 16 + m];
    const float s = f1r + mxh;
    Rr[rg] = __expf(fminf(60.f, -0.9f * s));
    br[rg] = (const uint4*)(bits32 + (size_t)(i0w + rg * 16 + m) * BROW + (jbase >> 5));
  }
  const float2* fp = es;
  const int r_st = t >> 3;
  const unsigned short* gB = whbt + (size_t)(h * 32 + r_st) * NNP + jbase + ((t & 7) ^ (r_st & 7)) * 8;
  f32x4 acc[2][2];
#pragma unroll
  for (int rg = 0; rg < 2; ++rg) {
    acc[rg][0] = (f32x4){0.f, 0.f, 0.f, 0.f};
    acc[rg][1] = (f32x4){0.f, 0.f, 0.f, 0.f};
  }

  __syncthreads();  // es ready

#pragma unroll
  for (int c = 0; c < 4; ++c) GL16(gB + c * 64, &bsm1[0][c * 2048 + t * 8]);

#pragma unroll
  for (int jc = 0; jc < 4; ++jc) {
    const int cur = jc & 1;
    uint4 bqq[2][2];
#pragma unroll
    for (int rg = 0; rg < 2; ++rg) {
      bqq[rg][0] = br[rg][jc * 2];
      bqq[rg][1] = br[rg][jc * 2 + 1];
    }
    if (jc < 3) {
#pragma unroll
      for (int c = 0; c < 4; ++c) GL16(gB + (jc + 1) * 256 + c * 64, &bsm1[cur ^ 1][c * 2048 + t * 8]);
      asm volatile("s_waitcnt vmcnt(4)" ::: "memory");
    } else {
      asm volatile("s_waitcnt vmcnt(0)" ::: "memory");
    }
    __builtin_amdgcn_s_barrier();
    __builtin_amdgcn_sched_barrier(0);
#pragma unroll
    for (int g = 0; g < 2; ++g) {
#pragma unroll
      for (int sub = 0; sub < 4; ++sub) {
        const int jl = (jc * 2 + g) * 128 + sub * 32;
        float4 e01 = *(const float4*)(fp + jl + q * 8);
        float4 e23 = *(const float4*)(fp + jl + q * 8 + 2);
        float4 e45 = *(const float4*)(fp + jl + q * 8 + 4);
        float4 e67 = *(const float4*)(fp + jl + q * 8 + 6);
        const int p = g * 16 + sub * 4 + q;
        short8_t b0 = *(const short8_t*)&bsm1[cur][(p >> 3) * 2048 + m * 64 + ((p & 7) ^ (m & 7)) * 8];
        short8_t b1 = *(const short8_t*)&bsm1[cur][(p >> 3) * 2048 + (m + 16) * 64 + ((p & 7) ^ ((m + 16) & 7)) * 8];
#pragma unroll
        for (int rg = 0; rg < 2; ++rg) {
          const uint4 bq = bqq[rg][g];
          unsigned bsel = (sub == 0 ? bq.x : sub == 1 ? bq.y : sub == 2 ? bq.z : bq.w) >> (q * 8);
          const float R = Rr[rg];
          auto sc = [&](float ep, float en, int jj) {
            float wv = fmaxf(ep, R * en);
            return ((bsel >> jj) & 1u) ? wv : 0.f;
          };
          union { short8_t v; unsigned u[4]; } A;
          A.u[0] = bfpk(sc(e01.x, e01.y, 0), sc(e01.z, e01.w, 1));
          A.u[1] = bfpk(sc(e23.x, e23.y, 2), sc(e23.z, e23.w, 3));
          A.u[2] = bfpk(sc(e45.x, e45.y, 4), sc(e45.z, e45.w, 5));
          A.u[3] = bfpk(sc(e67.x, e67.y, 6), sc(e67.z, e67.w, 7));
          acc[rg][0] = __builtin_amdgcn_mfma_f32_16x16x32_bf16(A.v, b0, acc[rg][0], 0, 0, 0);
          acc[rg][1] = __builtin_amdgcn_mfma_f32_16x16x32_bf16(A.v, b1, acc[rg][1], 0, 0, 0);
        }
      }
    }
    __builtin_amdgcn_sched_barrier(0);
    __builtin_amdgcn_s_barrier();
  }
#pragma unroll
  for (int rg = 0; rg < 2; ++rg) {
    float* pp = part + ((size_t)(js * 4 + h) * NN + i0w + rg * 16 + q * 4) * 32 + m;
#pragma unroll
    for (int r = 0; r < 4; ++r) {
      pp[r * 32] = acc[rg][0][r];
      pp[r * 32 + 16] = acc[rg][1][r];
    }
  }
}

// ---------------- fused: h1 combine + GEMM2 + f2/whbt2 + max2 ----------------
// grid 1024, block 256 (4 waves = 4 nodes)
__global__ __launch_bounds__(256) void k_fuseA(const float* __restrict__ part, const float* __restrict__ b1,
                                               const float* __restrict__ W2, const float* __restrict__ a2s,
                                               const float* __restrict__ a2d,
                                               unsigned short* __restrict__ whbt2,
                                               float* __restrict__ f1b, float* __restrict__ f2b,
                                               unsigned* __restrict__ mxu2) {
  const int t = threadIdx.x;
  __shared__ float W2s[H1DIM * H2DIM];
  __shared__ float h1s[4][124];
  __shared__ float f2red[4];
  for (int e = t; e < H1DIM * H2DIM; e += 256) W2s[e] = W2[e];
  const int wv = t >> 6, lane = t & 63;
  const int n = blockIdx.x * 4 + wv;
  const int h = lane >> 4, o2 = (lane & 15) * 2;
  float tot0 = 0.f, tot1 = 0.f;
#pragma unroll
  for (int z = 0; z < 4; ++z) {
    const float* pp = part + ((size_t)(z * 4 + h) * NN + n) * 32 + o2;
    float2 u = *(const float2*)pp;
    tot0 += u.x;
    tot1 += u.y;
  }
  float l = __shfl(tot0, h * 16 + 15);
  float inv = 1.f / l;
  if (o2 < 30) {
    h1s[wv][h * 30 + o2] = lrelu(tot0 * inv + b1[h * 30 + o2]);
    h1s[wv][h * 30 + o2 + 1] = lrelu(tot1 * inv + b1[h * 30 + o2 + 1]);
  }
  __syncthreads();
  const int o = lane;
  float acc = 0.f;
  if (o < H2DIM) {
    const float* hr = h1s[wv];
#pragma unroll 4
    for (int k = 0; k < H1DIM; ++k) acc += hr[k] * W2s[k * H2DIM + o];
  }
  unsigned short wbv = (o < H2DIM) ? bfrne(acc) : (o == H2DIM ? (unsigned short)0x3f80 : (unsigned short)0);
  whbt2[(size_t)o * NNP + n] = wbv;
  float ps = (o < H2DIM) ? acc * a2s[o] : 0.f;
  float pd = (o < H2DIM) ? acc * a2d[o] : 0.f;
  for (int off = 32; off > 0; off >>= 1) {
    ps += __shfl_down(ps, off);
    pd += __shfl_down(pd, off);
  }
  if (lane == 0) {
    f1b[n] = ps;
    f2b[n] = pd;
    f2red[wv] = pd;
  }
  __syncthreads();
  if (t == 0) {
    float m = fmaxf(fmaxf(f2red[0], f2red[1]), fmaxf(f2red[2], f2red[3]));
    atomicMax(mxu2, fenc(m));
  }
}

// ---------------- MFMA attention layer 2: BI=128, LDS-staged B (shared across waves) ----------------
// grid (32 i-blocks, 8 j-split), block 256; each wave covers 32 i-rows (2 row-groups)
__global__ __launch_bounds__(256) void k_att2m(const unsigned short* __restrict__ whbt2,
                                               const float* __restrict__ f1b, const float* __restrict__ f2b,
                                               const unsigned* __restrict__ mxu2,
                                               const unsigned int* __restrict__ bits32,
                                               float* __restrict__ part) {
  const int js = blockIdx.y;
  const int t = threadIdx.x;
  const int lane = t & 63, wave = t >> 6;
  const int m = lane & 15, q = lane >> 4;
  const int i0w = blockIdx.x * 128 + wave * 32;
  const int jbase = js * 512;
  const float mx0 = fdec(mxu2[0]);
  __shared__ float2 es[512];
  __shared__ unsigned short bsm2[2][8192];
  for (int e = t; e < 512; e += 256) {
    float fv = f2b[jbase + e] - mx0;
    es[e] = make_float2(__expf(fv), __expf(0.1f * fv));
  }
  float Rr[2];
  const uint4* br[2];
#pragma unroll
  for (int rg = 0; rg < 2; ++rg) {
    const float f1r = f1b[i0w + rg * 16 + m];
    const float s = f1r + mx0;
    Rr[rg] = __expf(fminf(60.f, -0.9f * s));
    br[rg] = (const uint4*)(bits32 + (size_t)(i0w + rg * 16 + m) * BROW + (jbase >> 5));
  }
  const float2* fp = es;
  const int r2 = t >> 2;
  const int sw2 = (r2 & 3) ^ ((r2 >> 2) & 3);
  const unsigned short* gB2 = whbt2 + (size_t)r2 * NNP + jbase + ((t & 3) ^ sw2) * 8;
  f32x4 acc[2][4];
#pragma unroll
  for (int rg = 0; rg < 2; ++rg)
#pragma unroll
    for (int xx = 0; xx < 4; ++xx) acc[rg][xx] = (f32x4){0.f, 0.f, 0.f, 0.f};

  __syncthreads();  // es ready

#pragma unroll
  for (int c = 0; c < 4; ++c) GL16(gB2 + c * 32, &bsm2[0][c * 2048 + t * 8]);

#pragma unroll
  for (int jc = 0; jc < 4; ++jc) {
    const int cur = jc & 1;
    uint4 bqr[2];
    bqr[0] = br[0][jc];
    bqr[1] = br[1][jc];
    if (jc < 3) {
#pragma unroll
      for (int c = 0; c < 4; ++c) GL16(gB2 + (jc + 1) * 128 + c * 32, &bsm2[cur ^ 1][c * 2048 + t * 8]);
      asm volatile("s_waitcnt vmcnt(4)" ::: "memory");
    } else {
      asm volatile("s_waitcnt vmcnt(0)" ::: "memory");
    }
    __builtin_amdgcn_s_barrier();
    __builtin_amdgcn_sched_barrier(0);
#pragma unroll
    for (int sub = 0; sub < 4; ++sub) {
      const int jl = jc * 128 + sub * 32;
      float4 e01 = *(const float4*)(fp + jl + q * 8);
      float4 e23 = *(const float4*)(fp + jl + q * 8 + 2);
      float4 e45 = *(const float4*)(fp + jl + q * 8 + 4);
      float4 e67 = *(const float4*)(fp + jl + q * 8 + 6);
      const int p = sub * 4 + q;
#pragma unroll
      for (int rg = 0; rg < 2; ++rg) {
        const uint4 bq = bqr[rg];
        unsigned bsel = (sub == 0 ? bq.x : sub == 1 ? bq.y : sub == 2 ? bq.z : bq.w) >> (q * 8);
        const float R = Rr[rg];
        auto sc = [&](float ep, float en, int jj) {
          float wv = fmaxf(ep, R * en);
          return ((bsel >> jj) & 1u) ? wv : 0.f;
        };
        union { short8_t v; unsigned u[4]; } A;
        A.u[0] = bfpk(sc(e01.x, e01.y, 0), sc(e01.z, e01.w, 1));
        A.u[1] = bfpk(sc(e23.x, e23.y, 2), sc(e23.z, e23.w, 3));
        A.u[2] = bfpk(sc(e45.x, e45.y, 4), sc(e45.z, e45.w, 5));
        A.u[3] = bfpk(sc(e67.x, e67.y, 6), sc(e67.z, e67.w, 7));
#pragma unroll
        for (int tile = 0; tile < 4; ++tile) {
          const int f = tile * 16 + m;
          const int sw = (f & 3) ^ ((f >> 2) & 3);
          short8_t b = *(const short8_t*)&bsm2[cur][(p >> 2) * 2048 + f * 32 + (((p & 3) ^ sw)) * 8];
          acc[rg][tile] = __builtin_amdgcn_mfma_f32_16x16x32_bf16(A.v, b, acc[rg][tile], 0, 0, 0);
        }
      }
    }
    __builtin_amdgcn_sched_barrier(0);
    __builtin_amdgcn_s_barrier();
  }
#pragma unroll
  for (int rg = 0; rg < 2; ++rg) {
    float* pp = part + ((size_t)js * NN + i0w + rg * 16 + q * 4) * 64 + m;
#pragma unroll
    for (int tile = 0; tile < 4; ++tile)
#pragma unroll
      for (int r = 0; r < 4; ++r) pp[r * 64 + tile * 16] = acc[rg][tile][r];
  }
}

// ---------------- fused: h2 combine + FiLM + logits ----------------
// grid 1024, block 256 (4 waves = 4 nodes)
__global__ __launch_bounds__(256) void k_fuseB(const float* __restrict__ part, const float* __restrict__ b2,
                                               const float* __restrict__ l_loc,
                                               const float* __restrict__ Wl1, const float* __restrict__ bl1,
                                               const float* __restrict__ Wl2, const float* __restrict__ bl2,
                                               const float* __restrict__ Wg, const float* __restrict__ bg,
                                               const float* __restrict__ Wb, const float* __restrict__ bb,
                                               const float* __restrict__ Wgate, const float* __restrict__ bgate,
                                               const float* __restrict__ Wc, float* __restrict__ logits) {
  const int t = threadIdx.x;
  const int wv = t >> 6, lane = t & 63;
  const int n = blockIdx.x * 4 + wv;
  const float* p = part + (size_t)n * 64 + lane;
  float tot = 0.f;
#pragma unroll
  for (int z = 0; z < 8; ++z) tot += p[(size_t)z * NN * 64];
  float l = __shfl(tot, 50);
  float hv = (lane < H2DIM) ? lrelu(tot / l + b2[lane]) : 0.f;
  // FiLM
  int r32 = lane & 31;
  float locv = l_loc[n * 16 + (lane & 15)];
  float cov = __shfl(locv, 15);
  cov = fminf(fmaxf(cov, 0.f), 1.f);
  float a1v = bl1[r32];
#pragma unroll
  for (int j = 0; j < 16; ++j) a1v += Wl1[r32 * 16 + j] * __shfl(locv, j);
  float z1 = lrelu(a1v);
  float a2v = bl2[r32];
#pragma unroll
  for (int j = 0; j < 32; ++j) a2v += Wl2[r32 * 32 + j] * __shfl(z1, j);
  float z2 = lrelu(a2v);
  float gs = bgate[0];
  float gam, bet;
  {
    int o = lane < H2DIM ? lane : 0;
    gam = bg[o];
    bet = bb[o];
#pragma unroll
    for (int j = 0; j < 32; ++j) {
      float zj = __shfl(z2, j);
      gs += Wgate[j] * zj;
      gam += Wg[o * 32 + j] * zj;
      bet += Wb[o * 32 + j] * zj;
    }
  }
  float g = cov / (1.f + __expf(-gs));
  float hf = hv + g * (gam * hv + bet);
  int o = lane < H2DIM ? lane : 0;
  float p0 = lane < H2DIM ? hf * Wc[o] : 0.f;
  float p1 = lane < H2DIM ? hf * Wc[H2DIM + o] : 0.f;
  for (int off = 32; off > 0; off >>= 1) {
    p0 += __shfl_down(p0, off);
    p1 += __shfl_down(p1, off);
  }
  if (lane == 0) {
    logits[n * 2 + 0] = lrelu(p0);
    logits[n * 2 + 1] = lrelu(p1);
  }
}

// ---------------- SSDB stage A: 240 parallel dot-products (no atomics) ----------------
// grid (60 k, 4 combos), block 64: hsum[combo*60+k] = lrelu(dot + bs1[k]) * Ws2[k]
__global__ __launch_bounds__(64) void k_ssdbA(const float* __restrict__ logits,
                                              const float* __restrict__ Ws1, const float* __restrict__ bs1,
                                              const float* __restrict__ Ws2, float* __restrict__ hsum) {
  const int k = blockIdx.x, combo = blockIdx.y;
  const int hemi = combo >> 1, c = combo & 1;
  const int lane = threadIdx.x;
  const float* wr = Ws1 + (size_t)k * 2048;
  const float* lc = logits + (size_t)hemi * 4096 + c;
  float acc = 0.f;
#pragma unroll 4
  for (int i = lane; i < 2048; i += 64) acc += wr[i] * lc[2 * i];
  for (int off = 32; off > 0; off >>= 1) acc += __shfl_down(acc, off);
  if (lane == 0) hsum[combo * 60 + k] = lrelu(acc + bs1[k]) * Ws2[k];
}

// ---------------- SSDB stage B + final output ----------------
// grid 33 x 256: each block redundantly reduces hsum -> Bs[4], writes its out-slice
__global__ __launch_bounds__(256) void k_finB(const float* __restrict__ hsum,
                                              const float* __restrict__ bs2,
                                              const float* __restrict__ logits,
                                              float* __restrict__ out) {
  __shared__ float Bs[4];
  const int t = threadIdx.x;
  {
    int combo = t >> 6, k = t & 63;
    float v = (k < 60) ? hsum[combo * 60 + k] : 0.f;
    for (int off = 32; off > 0; off >>= 1) v += __shfl_down(v, off);
    if (k == 0) Bs[combo] = lrelu(v + bs2[0]);
  }
  __syncthreads();
  int id = blockIdx.x * 256 + t;
  if (id < 2 * NN) {
    int n = id >> 1, c = id & 1;
    out[id] = logits[id] + Bs[(n < 2048 ? 0 : 2) + c];
  } else if (id < 2 * NN + 2) {
    int c = id - 2 * NN;
    out[id] = 0.5f * (Bs[c] + Bs[2 + c]);
  }
}

// ---------------- workspace layout (float offsets) ----------------
#define OFF_BITS 0          // 4096*66 u64 = 540672 f
#define OFF_W1T 540672      // 128*4128 shorts = 264192 f
#define OFF_GP 804864       // [16][4096][128] = 8388608 f; A1P/A2P overlay
#define OFF_A1P 804864      // [4][4][4096][32] = 2097152
#define OFF_A2P 804864      // [8][4096][64] = 2097152
#define OFF_WH1BT 9193472   // 128*4128 shorts = 264192 f
#define OFF_F1A 9457664     // [4][4096]
#define OFF_F2A 9474048     // [4][4096]
#define OFF_WH2BT 9490432   // 64*4128 shorts = 132096 f
#define OFF_F12 9622528     // 4096
#define OFF_F22 9626624     // 4096
#define OFF_LOG 9630720     // 8192
#define OFF_MX 9638912      // 8 uints: [0..3]=mxu1, [4]=mxu2
#define OFF_HS 9638976      // 240 floats (ssdb hsum)

extern "C" void kernel_launch(void* const* d_in, const int* in_sizes, int n_in,
                              void* d_out, int out_size, void* d_ws, size_t ws_size,
                              hipStream_t stream) {
  const float* x_fc  = (const float*)d_in[0];
  const int*   adj   = (const int*)d_in[1];
  const float* l_loc = (const float*)d_in[2];
  const float* W1    = (const float*)d_in[3];
  const float* a1s   = (const float*)d_in[4];
  const float* a1d   = (const float*)d_in[5];
  const float* b1    = (const float*)d_in[6];
  const float* W2    = (const float*)d_in[7];
  const float* a2s   = (const float*)d_in[8];
  const float* a2d   = (const float*)d_in[9];
  const float* b2    = (const float*)d_in[10];
  const float* Wc    = (const float*)d_in[11];
  const float* Wl1   = (const float*)d_in[12];
  const float* bl1   = (const float*)d_in[13];
  const float* Wl2   = (const float*)d_in[14];
  const float* bl2   = (const float*)d_in[15];
  const float* Wg    = (const float*)d_in[16];
  const float* bg    = (const float*)d_in[17];
  const float* Wb    = (const float*)d_in[18];
  const float* bb    = (const float*)d_in[19];
  const float* Wgate = (const float*)d_in[20];
  const float* bgate = (const float*)d_in[21];
  const float* Ws1   = (const float*)d_in[22];
  const float* bs1   = (const float*)d_in[23];
  const float* Ws2   = (const float*)d_in[24];
  const float* bs2   = (const float*)d_in[25];
  float* out = (float*)d_out;
  float* w = (float*)d_ws;
  unsigned long long* bits = (unsigned long long*)(w + OFF_BITS);
  const unsigned int* bits32 = (const unsigned int*)bits;
  unsigned short* wh1bt = (unsigned short*)(w + OFF_WH1BT);
  unsigned short* wh2bt = (unsigned short*)(w + OFF_WH2BT);
  unsigned short* w1t = (unsigned short*)(w + OFF_W1T);
  unsigned* mxu = (unsigned*)(w + OFF_MX);

  k_pre<<<16, 256, 0, stream>>>(W1, a1s, a1d, w1t, mxu);
  k_gb<<<16896, 256, 0, stream>>>(x_fc, w1t, w + OFF_GP, adj, bits);
  k_f1c<<<256, 256, 0, stream>>>(w + OFF_GP, wh1bt, w + OFF_F1A, w + OFF_F2A, mxu);
  k_att1m<<<dim3(32, HEADS, 4), 256, 0, stream>>>(wh1bt, w + OFF_F1A, w + OFF_F2A,
                                                  mxu, bits32, w + OFF_A1P);
  k_fuseA<<<1024, 256, 0, stream>>>(w + OFF_A1P, b1, W2, a2s, a2d, wh2bt,
                                    w + OFF_F12, w + OFF_F22, mxu + 4);
  k_att2m<<<dim3(32, 8), 256, 0, stream>>>(wh2bt, w + OFF_F12, w + OFF_F22,
                                           mxu + 4, bits32, w + OFF_A2P);
  k_fuseB<<<1024, 256, 0, stream>>>(w + OFF_A2P, b2, l_loc, Wl1, bl1, Wl2, bl2,
                                    Wg, bg, Wb, bb, Wgate, bgate, Wc, w + OFF_LOG);
  k_ssdbA<<<dim3(60, 4), 64, 0, stream>>>(w + OFF_LOG, Ws1, bs1, Ws2, w + OFF_HS);
  k_finB<<<33, 256, 0, stream>>>(w + OFF_HS, bs2, w + OFF_LOG, out);
}